// Round 4
// baseline (3186.935 us; speedup 1.0000x reference)
//
#include <hip/hip_runtime.h>
#include <hip/hip_bf16.h>

// Problem constants (fixed by the reference)
#define B_  64
#define T_  128
#define E_  300
#define EP  320     // E padded to multiple of 32 for MFMA K-loop
#define H_  512
#define G4  2048    // 4*H
#define R_  128     // 2*B (s1+s2 batched; shared LSTM weights)
#define C_  256
#define M_  512
#define TS  (T_ + 1)  // h time slots: slot 0 = h0, slot t+1 = h(t)
#define NB  256     // persistent-kernel grid size

typedef short bf16x8 __attribute__((ext_vector_type(8)));
typedef float f32x4  __attribute__((ext_vector_type(4)));
#define MFMA(a, b, c) __builtin_amdgcn_mfma_f32_16x16x32_bf16((a), (b), (c), 0, 0, 0)

__device__ __forceinline__ float fsig(float x) { return 1.0f / (1.0f + __expf(-x)); }
__device__ __forceinline__ float ftanh(float x) {
    float a = fminf(fabsf(x), 15.0f);
    float e = __expf(2.0f * a);
    return copysignf((e - 1.0f) / (e + 1.0f), x);
}
__device__ __forceinline__ ushort f2bf(float f) {
    __hip_bfloat16 h = __float2bfloat16(f);
    return *reinterpret_cast<ushort*>(&h);
}
__device__ __forceinline__ float bf2f(ushort u) {
    __hip_bfloat16 h = *reinterpret_cast<__hip_bfloat16*>(&u);
    return __bfloat162float(h);
}

// ---------------------------------------------------------------------------
// P0: f32 -> bf16 row-wise convert with K padding (zeros in [sk, dk)).
// ---------------------------------------------------------------------------
__global__ __launch_bounds__(256) void k_cvt(const float* __restrict__ src,
                                             ushort* __restrict__ dst,
                                             int sk, int dk)
{
    const int r = blockIdx.x;
    for (int c = threadIdx.x; c < dk; c += 256)
        dst[(long)r * dk + c] = (c < sk) ? f2bf(src[(long)r * sk + c]) : (ushort)0;
}

// P1: init h slot 0 (bf16) from the h0 inputs.
__global__ __launch_bounds__(256) void k_init(
    const float* __restrict__ s1_h0, const float* __restrict__ s2_h0,
    ushort* __restrict__ hfB, ushort* __restrict__ hbB)
{
    const int r = blockIdx.x;                    // 0..127
    const int rl = (r < B_) ? r : r - B_;
    const float* h0 = (r < B_) ? s1_h0 : s2_h0;  // [2][B][H]
    for (int j = threadIdx.x; j < H_; j += 256) {
        hfB[(long)r * TS * H_ + j] = f2bf(h0[(long)0 * B_ * H_ + (long)rl * H_ + j]);
        hbB[(long)r * TS * H_ + j] = f2bf(h0[(long)1 * B_ * H_ + (long)rl * H_ + j]);
    }
}

// ---------------------------------------------------------------------------
// K1: embedding gather + input GEMM via bf16 MFMA (unchanged from round 3).
// ---------------------------------------------------------------------------
__global__ __launch_bounds__(256) void k_embed_mfma(
    const int* __restrict__ s1, const int* __restrict__ s2,
    const int* __restrict__ l1, const int* __restrict__ l2,
    const ushort* __restrict__ embB,
    const ushort* __restrict__ WihBf, const ushort* __restrict__ WihBb,
    const float* __restrict__ b_f, const float* __restrict__ b_b,
    ushort* __restrict__ xf, ushort* __restrict__ xb)
{
    const int dir = blockIdx.z;
    const int r   = blockIdx.y >> 1;
    const int t0  = (blockIdx.y & 1) * 64;
    const int N0  = blockIdx.x * 128;
    const int L   = (r < B_) ? l1[r] : l2[r - B_];
    if (L <= t0) return;

    const int tid = threadIdx.x;
    const int lane = tid & 63, w = tid >> 6;
    const int wm = w & 1, wn = w >> 1;
    const int l15 = lane & 15, q8 = (lane >> 4) * 8;

    __shared__ int toks[64];
    __shared__ __align__(16) ushort As[64][40];
    __shared__ __align__(16) ushort Bs[128][40];

    if (tid < 64) {
        int t  = t0 + tid;
        int tt = dir ? ((t < L) ? (L - 1 - t) : t) : t;
        toks[tid] = (r < B_) ? s1[r * T_ + tt] : s2[(r - B_) * T_ + tt];
    }
    __syncthreads();

    const ushort* Wih  = dir ? WihBb : WihBf;
    const float*  bias = dir ? b_b : b_f;

    f32x4 acc[2][4] = {};

    for (int k0 = 0; k0 < EP; k0 += 32) {
        {   // A: 64 rows x 32 k
            int row = tid >> 2, seg = tid & 3;
            *(uint4*)&As[row][seg * 8] =
                *(const uint4*)&embB[(long)toks[row] * EP + k0 + seg * 8];
        }
#pragma unroll
        for (int p = 0; p < 2; ++p) {   // B: 128 cols x 32 k
            int u = tid + p * 256;
            int row = u >> 2, seg = u & 3;
            *(uint4*)&Bs[row][seg * 8] =
                *(const uint4*)&Wih[(long)(N0 + row) * EP + k0 + seg * 8];
        }
        __syncthreads();
        bf16x8 af[2], bfr[4];
#pragma unroll
        for (int mt = 0; mt < 2; ++mt)
            af[mt] = *(const bf16x8*)&As[wm * 32 + mt * 16 + l15][q8];
#pragma unroll
        for (int nt = 0; nt < 4; ++nt)
            bfr[nt] = *(const bf16x8*)&Bs[wn * 64 + nt * 16 + l15][q8];
#pragma unroll
        for (int mt = 0; mt < 2; ++mt)
#pragma unroll
            for (int nt = 0; nt < 4; ++nt)
                acc[mt][nt] = MFMA(af[mt], bfr[nt], acc[mt][nt]);
        __syncthreads();
    }

    ushort* xout = dir ? xb : xf;
#pragma unroll
    for (int mt = 0; mt < 2; ++mt) {
        int m = r * T_ + t0 + wm * 32 + mt * 16 + (lane >> 4) * 4;
#pragma unroll
        for (int nt = 0; nt < 4; ++nt) {
            int col = N0 + wn * 64 + nt * 16 + l15;
            float bv = bias[col];
#pragma unroll
            for (int rg = 0; rg < 4; ++rg)
                xout[(long)(m + rg) * G4 + col] = f2bf(acc[mt][nt][rg] + bv);
        }
    }
}

// ---------------------------------------------------------------------------
// K2 v3: PERSISTENT recurrence — all 128 steps in one launch.
// Grid 256 = 2 streams x 4 rowblocks(32) x 32 jblocks(16); 1 block owns its
// 32x16 cells for the whole sequence. Whh B-fragments in registers (64 VGPR,
// loaded once); c in 2 VGPRs/thread; h exchanged via agent-scope write-through
// stores + monotonic count/gen grid barrier between steps.
// Co-residency: LDS 42.5 KB -> 3 blocks/CU capacity; 256 blocks always fit.
// ---------------------------------------------------------------------------
__global__ __launch_bounds__(256) void k_recur(
    const ushort* __restrict__ xf, const ushort* __restrict__ xb,
    ushort* __restrict__ hfB, ushort* __restrict__ hbB,
    const ushort* __restrict__ WhhBf, const ushort* __restrict__ WhhBb,
    const float* __restrict__ s1_c0, const float* __restrict__ s2_c0,
    int* __restrict__ bar)
{
    const int bx = blockIdx.x;
    const int s  = bx >> 7;          // stream: 0 fwd, 1 bwd
    const int rb = (bx >> 5) & 3;    // row block of 32
    const int jb = bx & 31;          // j block of 16
    const int r0 = rb * 32, j0 = jb * 16;

    const ushort* xW  = s ? xb : xf;
    const ushort* Whh = s ? WhhBb : WhhBf;
    ushort* hB = s ? hbB : hfB;

    const int tid = threadIdx.x;
    const int lane = tid & 63;
    const int g = tid >> 6;          // wave = gate (i,f,g,o)
    const int l15 = lane & 15, q8 = (lane >> 4) * 8;

    __shared__ __align__(16) ushort As[32][520];   // 32 rows x 512 k (full K)
    __shared__ float Gs[4][32][18];                // gate pre-acts 32 x 16

    // --- Whh fragments resident in registers: wave g, cols j0+l15, K=512 ---
    bf16x8 bfr[16];
    {
        const ushort* brow = &Whh[((long)g * H_ + j0 + l15) * H_];
#pragma unroll
        for (int ks = 0; ks < 16; ++ks)
            bfr[ks] = *(const bf16x8*)&brow[ks * 32 + q8];
    }

    // --- cell ownership: thread -> (row rr, j-pair jj) ---
    const int rr = tid >> 3, jj = (tid & 7) * 2;
    const int rg_ = r0 + rr;
    const int rl  = (rg_ < B_) ? rg_ : rg_ - B_;
    const float* c0p = (rg_ < B_) ? s1_c0 : s2_c0;   // [2][B][H]
    float c_0 = c0p[(long)s * B_ * H_ + (long)rl * H_ + j0 + jj];
    float c_1 = c0p[(long)s * B_ * H_ + (long)rl * H_ + j0 + jj + 1];

    // A staging: thread loads 8 uint4 (row arow, all K slices)
    const int arow = tid >> 3, aseg = tid & 7;

    for (int t = 0; t < T_; ++t) {
        if (t) {   // grid barrier: h(t) fully written before anyone reads it
            __syncthreads();
            if (tid == 0) {
                __threadfence();   // release: drain + make block's writes device-visible
                int arrive = __hip_atomic_fetch_add(&bar[0], 1, __ATOMIC_ACQ_REL,
                                                    __HIP_MEMORY_SCOPE_AGENT);
                if (arrive == t * NB - 1) {
                    __hip_atomic_fetch_add(&bar[16], 1, __ATOMIC_RELEASE,
                                           __HIP_MEMORY_SCOPE_AGENT);
                } else {
                    while (__hip_atomic_load(&bar[16], __ATOMIC_ACQUIRE,
                                             __HIP_MEMORY_SCOPE_AGENT) < t)
                        __builtin_amdgcn_s_sleep(1);
                }
            }
            __syncthreads();
        }

        // stage h(t) rows r0..r0+31, full K=512
        uint4 av[8];
        const long habase = ((long)(r0 + arow) * TS + t) * H_ + aseg * 8;
#pragma unroll
        for (int sl = 0; sl < 8; ++sl)
            av[sl] = *(const uint4*)&hB[habase + sl * 64];

        // xW gate pre-activations for this thread's 2 cells (4 gates)
        uint xw[4];
        const long xbase = ((long)rg_ * T_ + t) * G4 + j0 + jj;
#pragma unroll
        for (int gg = 0; gg < 4; ++gg)
            xw[gg] = *(const uint*)&xW[xbase + gg * H_];

#pragma unroll
        for (int sl = 0; sl < 8; ++sl)
            *(uint4*)&As[arow][sl * 64 + aseg * 8] = av[sl];
        __syncthreads();

        f32x4 acc0 = {}, acc1 = {};
#pragma unroll
        for (int ks = 0; ks < 16; ++ks) {
            bf16x8 a0 = *(const bf16x8*)&As[l15][ks * 32 + q8];
            bf16x8 a1 = *(const bf16x8*)&As[16 + l15][ks * 32 + q8];
            acc0 = MFMA(a0, bfr[ks], acc0);
            acc1 = MFMA(a1, bfr[ks], acc1);
        }

        // publish gate pre-acts (C layout: col=lane&15, row=(lane>>4)*4+rg)
#pragma unroll
        for (int rg2 = 0; rg2 < 4; ++rg2) {
            Gs[g][(lane >> 4) * 4 + rg2][l15]      = acc0[rg2];
            Gs[g][16 + (lane >> 4) * 4 + rg2][l15] = acc1[rg2];
        }
        __syncthreads();

        // fused cell update for 2 adjacent cells
        float gi0 = Gs[0][rr][jj]     + bf2f((ushort)(xw[0] & 0xffff));
        float gi1 = Gs[0][rr][jj + 1] + bf2f((ushort)(xw[0] >> 16));
        float gf0 = Gs[1][rr][jj]     + bf2f((ushort)(xw[1] & 0xffff));
        float gf1 = Gs[1][rr][jj + 1] + bf2f((ushort)(xw[1] >> 16));
        float gg0 = Gs[2][rr][jj]     + bf2f((ushort)(xw[2] & 0xffff));
        float gg1 = Gs[2][rr][jj + 1] + bf2f((ushort)(xw[2] >> 16));
        float go0 = Gs[3][rr][jj]     + bf2f((ushort)(xw[3] & 0xffff));
        float go1 = Gs[3][rr][jj + 1] + bf2f((ushort)(xw[3] >> 16));

        c_0 = fsig(gf0) * c_0 + fsig(gi0) * ftanh(gg0);
        c_1 = fsig(gf1) * c_1 + fsig(gi1) * ftanh(gg1);
        float h0 = fsig(go0) * ftanh(c_0);
        float h1 = fsig(go1) * ftanh(c_1);

        uint hp = (uint)f2bf(h0) | ((uint)f2bf(h1) << 16);
        // agent-scope write-through: device-coherent without L2 writeback
        __hip_atomic_store((uint*)&hB[((long)rg_ * TS + t + 1) * H_ + j0 + jj],
                           hp, __ATOMIC_RELAXED, __HIP_MEMORY_SCOPE_AGENT);
    }
}

// ---------------------------------------------------------------------------
// K3a: U[m,c] = tanh(Hout[m,:] @ S1W^T) via bf16 MFMA (unchanged).
// ---------------------------------------------------------------------------
__global__ __launch_bounds__(256) void k_attn_mfma(
    const ushort* __restrict__ hfB, const ushort* __restrict__ hbB,
    const int* __restrict__ l1, const int* __restrict__ l2,
    const ushort* __restrict__ S1WB, float* __restrict__ U)
{
    const int r  = blockIdx.y >> 1;
    const int t0 = (blockIdx.y & 1) * 64;
    const int N0 = blockIdx.x * 64;
    const int L  = (r < B_) ? l1[r] : l2[r - B_];
    if (L <= t0) return;

    const int tid = threadIdx.x;
    const int lane = tid & 63, w = tid >> 6;
    const int wm = w & 1, wn = w >> 1;
    const int l15 = lane & 15, q8 = (lane >> 4) * 8;

    __shared__ __align__(16) ushort As[64][72];
    __shared__ __align__(16) ushort Bs[64][72];

    f32x4 acc[2][2] = {};

    for (int k0 = 0; k0 < 2 * H_; k0 += 64) {
#pragma unroll
        for (int p = 0; p < 2; ++p) {   // A: 64 rows x 64 k
            int u = tid + p * 256;
            int row = u >> 3, seg = u & 7;
            int tpos = t0 + row;
            int k = k0 + seg * 8;
            long idx;
            const ushort* src;
            if (k0 < H_) {
                src = hfB; idx = ((long)r * TS + tpos + 1) * H_ + k;
            } else {
                int tt = (tpos < L) ? (L - 1 - tpos) : tpos;
                src = hbB; idx = ((long)r * TS + tt + 1) * H_ + (k - H_);
            }
            *(uint4*)&As[row][seg * 8] = *(const uint4*)&src[idx];
        }
#pragma unroll
        for (int p = 0; p < 2; ++p) {   // B: 64 cols x 64 k
            int u = tid + p * 256;
            int row = u >> 3, seg = u & 7;
            *(uint4*)&Bs[row][seg * 8] =
                *(const uint4*)&S1WB[(long)(N0 + row) * (2 * H_) + k0 + seg * 8];
        }
        __syncthreads();
#pragma unroll
        for (int ks = 0; ks < 2; ++ks) {
            bf16x8 a0 = *(const bf16x8*)&As[wm * 32 + l15][ks * 32 + q8];
            bf16x8 a1 = *(const bf16x8*)&As[wm * 32 + 16 + l15][ks * 32 + q8];
            bf16x8 b0 = *(const bf16x8*)&Bs[wn * 32 + l15][ks * 32 + q8];
            bf16x8 b1 = *(const bf16x8*)&Bs[wn * 32 + 16 + l15][ks * 32 + q8];
            acc[0][0] = MFMA(a0, b0, acc[0][0]);
            acc[0][1] = MFMA(a0, b1, acc[0][1]);
            acc[1][0] = MFMA(a1, b0, acc[1][0]);
            acc[1][1] = MFMA(a1, b1, acc[1][1]);
        }
        __syncthreads();
    }
#pragma unroll
    for (int mt = 0; mt < 2; ++mt) {
        int m = r * T_ + t0 + wm * 32 + mt * 16 + (lane >> 4) * 4;
#pragma unroll
        for (int nt = 0; nt < 2; ++nt) {
            int col = N0 + wn * 32 + nt * 16 + l15;
#pragma unroll
            for (int rg = 0; rg < 4; ++rg)
                U[(long)(m + rg) * C_ + col] = ftanh(acc[mt][nt][rg]);
        }
    }
}

// ---------------------------------------------------------------------------
// K3b: scores = U@S2W, masked softmax, pooled = attn @ Hout (unchanged).
// ---------------------------------------------------------------------------
__global__ __launch_bounds__(256) void k_attn_pool(
    const ushort* __restrict__ hfB, const ushort* __restrict__ hbB,
    const float* __restrict__ U, const float* __restrict__ S2W,
    const int* __restrict__ l1, const int* __restrict__ l2,
    float* __restrict__ pooled)
{
    const int r = blockIdx.x;
    const int L = (r < B_) ? l1[r] : l2[r - B_];
    const int tid = threadIdx.x;
    const int lane = tid & 63, w = tid >> 6;

    __shared__ float att[T_];

    for (int tt = w; tt < T_; tt += 4) {
        float p = 0.0f;
        if (tt < L) {
            const float* u = &U[(long)(r * T_ + tt) * C_];
            p = u[lane] * S2W[lane] + u[lane + 64] * S2W[lane + 64]
              + u[lane + 128] * S2W[lane + 128] + u[lane + 192] * S2W[lane + 192];
            for (int off = 32; off; off >>= 1) p += __shfl_down(p, off);
        }
        if (lane == 0) att[tt] = p;
    }
    __syncthreads();

    float mx = -1e30f;
    for (int tt = 0; tt < L; ++tt) mx = fmaxf(mx, att[tt]);
    __syncthreads();
    if (tid < T_) att[tid] = (tid < L) ? __expf(att[tid] - mx) : 0.0f;
    __syncthreads();
    float sum = 0.0f;
    for (int tt = 0; tt < L; ++tt) sum += att[tt];
    float inv = 1.0f / sum;

    for (int d = tid; d < 2 * H_; d += 256) {
        float a = 0.0f;
        for (int tt = 0; tt < L; ++tt) {
            float hv = (d < H_)
                ? bf2f(hfB[((long)r * TS + tt + 1) * H_ + d])
                : bf2f(hbB[((long)r * TS + (L - tt)) * H_ + (d - H_)]);
            a += att[tt] * hv;
        }
        pooled[(long)r * (2 * H_) + d] = a * inv;
    }
}

// ---------------------------------------------------------------------------
// K4a: om[b][mm] = merged[b] . mlpW[mm] + mlpb[mm] (unchanged from round 3).
// ---------------------------------------------------------------------------
__global__ __launch_bounds__(256) void k_mlp1(
    const float* __restrict__ pooled,
    const float* __restrict__ mlpW, const float* __restrict__ mlpb,
    float* __restrict__ om)
{
    const int mg = blockIdx.x;      // 0..7
    const int b  = blockIdx.y;      // 0..63
    const int tid = threadIdx.x;
    const int lane = tid & 63, w = tid >> 6;

    __shared__ __align__(16) float sm[2048];

#pragma unroll
    for (int it = 0; it < 8; ++it) {
        int d = tid + it * 256;
        float v;
        if (d < 1024) {
            v = pooled[(long)b * 1024 + d] + pooled[(long)(B_ + b) * 1024 + d];
        } else {
            int dd = d - 1024;
            float x = pooled[(long)b * 1024 + dd] - pooled[(long)(B_ + b) * 1024 + dd];
            v = x * x;
        }
        sm[d] = v;
    }
    __syncthreads();

    for (int i = 0; i < 16; ++i) {
        int mm = mg * 64 + w * 16 + i;
        const float* wrow = &mlpW[(long)mm * 2048];
        float ax = 0.f, ay = 0.f, az = 0.f, aw = 0.f;
#pragma unroll
        for (int it = 0; it < 8; ++it) {
            int k = it * 256 + lane * 4;
            float4 wv = *(const float4*)&wrow[k];
            float4 sv = *(const float4*)&sm[k];
            ax += wv.x * sv.x; ay += wv.y * sv.y;
            az += wv.z * sv.z; aw += wv.w * sv.w;
        }
        float ssum = (ax + ay) + (az + aw);
        for (int off = 32; off; off >>= 1) ssum += __shfl_down(ssum, off);
        if (lane == 0) om[(long)b * M_ + mm] = ssum + mlpb[mm];
    }
}

// K4b: out[b] = sigmoid(om[b] . outW + outb)   (CLS = 1)
__global__ __launch_bounds__(256) void k_final(
    const float* __restrict__ om,
    const float* __restrict__ outW, const float* __restrict__ outb,
    float* __restrict__ out)
{
    const int b = blockIdx.x;
    const int tid = threadIdx.x;
    __shared__ float red[256];
    float p = om[(long)b * M_ + tid] * outW[tid]
            + om[(long)b * M_ + 256 + tid] * outW[256 + tid];
    red[tid] = p;
    __syncthreads();
    for (int off = 128; off > 0; off >>= 1) {
        if (tid < off) red[tid] += red[tid + off];
        __syncthreads();
    }
    if (tid == 0) out[b] = 1.0f / (1.0f + __expf(-(red[0] + outb[0])));
}

// ---------------------------------------------------------------------------
extern "C" void kernel_launch(void* const* d_in, const int* in_sizes, int n_in,
                              void* d_out, int out_size, void* d_ws, size_t ws_size,
                              hipStream_t stream)
{
    const int*   s1    = (const int*)d_in[0];
    const int*   s2    = (const int*)d_in[1];
    const int*   l1    = (const int*)d_in[2];
    const int*   l2    = (const int*)d_in[3];
    const float* s1_h0 = (const float*)d_in[4];
    const float* s1_c0 = (const float*)d_in[5];
    const float* s2_h0 = (const float*)d_in[6];
    const float* s2_c0 = (const float*)d_in[7];
    const float* emb   = (const float*)d_in[8];
    const float* Wih_f = (const float*)d_in[9];
    const float* Whh_f = (const float*)d_in[10];
    const float* b_f   = (const float*)d_in[11];
    const float* Wih_b = (const float*)d_in[12];
    const float* Whh_b = (const float*)d_in[13];
    const float* b_b   = (const float*)d_in[14];
    const float* S1W   = (const float*)d_in[15];
    const float* S2W   = (const float*)d_in[16];
    const float* mlpW  = (const float*)d_in[17];
    const float* mlpb  = (const float*)d_in[18];
    const float* outW  = (const float*)d_in[19];
    const float* outb  = (const float*)d_in[20];
    float* out = (float*)d_out;

    // Workspace carve (all 16B-aligned)
    ushort* p16 = (ushort*)d_ws;
    ushort* embB  = p16;  p16 += (long)32000 * EP;
    ushort* WihBf = p16;  p16 += (long)G4 * EP;
    ushort* WihBb = p16;  p16 += (long)G4 * EP;
    ushort* WhhBf = p16;  p16 += (long)G4 * H_;
    ushort* WhhBb = p16;  p16 += (long)G4 * H_;
    ushort* S1WB  = p16;  p16 += (long)C_ * 2 * H_;
    ushort* xf    = p16;  p16 += (long)R_ * T_ * G4;
    ushort* xb    = p16;  p16 += (long)R_ * T_ * G4;
    ushort* hfB   = p16;  p16 += (long)R_ * TS * H_;
    ushort* hbB   = p16;  p16 += (long)R_ * TS * H_;
    float* pf = (float*)p16;
    float* U      = pf;   pf += (long)R_ * T_ * C_;
    float* pooled = pf;   pf += (long)R_ * 2 * H_;
    float* om     = pf;   pf += (long)B_ * M_;
    int*   bar    = (int*)pf;   // 128 B barrier state (bar[0]=count, bar[16]=gen)

    // barrier init (memset node; graph-capture-safe)
    hipMemsetAsync(bar, 0, 128, stream);

    // P0/P1: weight conversion + state init
    k_cvt<<<32000, 256, 0, stream>>>(emb,   embB,  E_, EP);
    k_cvt<<<G4,    256, 0, stream>>>(Wih_f, WihBf, E_, EP);
    k_cvt<<<G4,    256, 0, stream>>>(Wih_b, WihBb, E_, EP);
    k_cvt<<<G4,    256, 0, stream>>>(Whh_f, WhhBf, H_, H_);
    k_cvt<<<G4,    256, 0, stream>>>(Whh_b, WhhBb, H_, H_);
    k_cvt<<<C_,    256, 0, stream>>>(S1W,   S1WB,  2 * H_, 2 * H_);
    k_init<<<R_, 256, 0, stream>>>(s1_h0, s2_h0, hfB, hbB);

    // K1: input GEMM
    k_embed_mfma<<<dim3(16, 256, 2), 256, 0, stream>>>(
        s1, s2, l1, l2, embB, WihBf, WihBb, b_f, b_b, xf, xb);

    // K2: full recurrence in ONE persistent launch
    k_recur<<<NB, 256, 0, stream>>>(xf, xb, hfB, hbB, WhhBf, WhhBb,
                                    s1_c0, s2_c0, bar);

    // K3: attention pooling
    k_attn_mfma<<<dim3(4, 256), 256, 0, stream>>>(hfB, hbB, l1, l2, S1WB, U);
    k_attn_pool<<<R_, 256, 0, stream>>>(hfB, hbB, U, S2W, l1, l2, pooled);

    // K4: MLP head
    k_mlp1<<<dim3(8, B_), 256, 0, stream>>>(pooled, mlpW, mlpb, om);
    k_final<<<B_, 256, 0, stream>>>(om, outW, outb, out);
}

// Round 6
// 1856.535 us; speedup vs baseline: 1.7166x; 1.7166x over previous
//
#include <hip/hip_runtime.h>
#include <hip/hip_bf16.h>

// Problem constants (fixed by the reference)
#define B_  64
#define T_  128
#define E_  300
#define EP  320     // E padded to multiple of 32 for MFMA K-loop
#define H_  512
#define G4  2048    // 4*H
#define R_  128     // 2*B (s1+s2 batched; shared LSTM weights)
#define C_  256
#define M_  512
#define TS  (T_ + 1)  // h time slots: slot 0 = h0, slot t+1 = h(t)
#define NB  256     // persistent-kernel grid size

typedef short bf16x8 __attribute__((ext_vector_type(8)));
typedef float f32x4  __attribute__((ext_vector_type(4)));
#define MFMA(a, b, c) __builtin_amdgcn_mfma_f32_16x16x32_bf16((a), (b), (c), 0, 0, 0)

__device__ __forceinline__ float fsig(float x) { return 1.0f / (1.0f + __expf(-x)); }
__device__ __forceinline__ float ftanh(float x) {
    float a = fminf(fabsf(x), 15.0f);
    float e = __expf(2.0f * a);
    return copysignf((e - 1.0f) / (e + 1.0f), x);
}
__device__ __forceinline__ ushort f2bf(float f) {
    __hip_bfloat16 h = __float2bfloat16(f);
    return *reinterpret_cast<ushort*>(&h);
}
__device__ __forceinline__ float bf2f(ushort u) {
    __hip_bfloat16 h = *reinterpret_cast<__hip_bfloat16*>(&u);
    return __bfloat162float(h);
}

// ---------------------------------------------------------------------------
// P0: f32 -> bf16 row-wise convert with K padding (zeros in [sk, dk)).
// ---------------------------------------------------------------------------
__global__ __launch_bounds__(256) void k_cvt(const float* __restrict__ src,
                                             ushort* __restrict__ dst,
                                             int sk, int dk)
{
    const int r = blockIdx.x;
    for (int c = threadIdx.x; c < dk; c += 256)
        dst[(long)r * dk + c] = (c < sk) ? f2bf(src[(long)r * sk + c]) : (ushort)0;
}

// P1: init h slot 0 (bf16) from the h0 inputs.
__global__ __launch_bounds__(256) void k_init(
    const float* __restrict__ s1_h0, const float* __restrict__ s2_h0,
    ushort* __restrict__ hfB, ushort* __restrict__ hbB)
{
    const int r = blockIdx.x;                    // 0..127
    const int rl = (r < B_) ? r : r - B_;
    const float* h0 = (r < B_) ? s1_h0 : s2_h0;  // [2][B][H]
    for (int j = threadIdx.x; j < H_; j += 256) {
        hfB[(long)r * TS * H_ + j] = f2bf(h0[(long)0 * B_ * H_ + (long)rl * H_ + j]);
        hbB[(long)r * TS * H_ + j] = f2bf(h0[(long)1 * B_ * H_ + (long)rl * H_ + j]);
    }
}

// ---------------------------------------------------------------------------
// K1: embedding gather + input GEMM via bf16 MFMA (unchanged).
// ---------------------------------------------------------------------------
__global__ __launch_bounds__(256) void k_embed_mfma(
    const int* __restrict__ s1, const int* __restrict__ s2,
    const int* __restrict__ l1, const int* __restrict__ l2,
    const ushort* __restrict__ embB,
    const ushort* __restrict__ WihBf, const ushort* __restrict__ WihBb,
    const float* __restrict__ b_f, const float* __restrict__ b_b,
    ushort* __restrict__ xf, ushort* __restrict__ xb)
{
    const int dir = blockIdx.z;
    const int r   = blockIdx.y >> 1;
    const int t0  = (blockIdx.y & 1) * 64;
    const int N0  = blockIdx.x * 128;
    const int L   = (r < B_) ? l1[r] : l2[r - B_];
    if (L <= t0) return;

    const int tid = threadIdx.x;
    const int lane = tid & 63, w = tid >> 6;
    const int wm = w & 1, wn = w >> 1;
    const int l15 = lane & 15, q8 = (lane >> 4) * 8;

    __shared__ int toks[64];
    __shared__ __align__(16) ushort As[64][40];
    __shared__ __align__(16) ushort Bs[128][40];

    if (tid < 64) {
        int t  = t0 + tid;
        int tt = dir ? ((t < L) ? (L - 1 - t) : t) : t;
        toks[tid] = (r < B_) ? s1[r * T_ + tt] : s2[(r - B_) * T_ + tt];
    }
    __syncthreads();

    const ushort* Wih  = dir ? WihBb : WihBf;
    const float*  bias = dir ? b_b : b_f;

    f32x4 acc[2][4] = {};

    for (int k0 = 0; k0 < EP; k0 += 32) {
        {   // A: 64 rows x 32 k
            int row = tid >> 2, seg = tid & 3;
            *(uint4*)&As[row][seg * 8] =
                *(const uint4*)&embB[(long)toks[row] * EP + k0 + seg * 8];
        }
#pragma unroll
        for (int p = 0; p < 2; ++p) {   // B: 128 cols x 32 k
            int u = tid + p * 256;
            int row = u >> 2, seg = u & 3;
            *(uint4*)&Bs[row][seg * 8] =
                *(const uint4*)&Wih[(long)(N0 + row) * EP + k0 + seg * 8];
        }
        __syncthreads();
        bf16x8 af[2], bfr[4];
#pragma unroll
        for (int mt = 0; mt < 2; ++mt)
            af[mt] = *(const bf16x8*)&As[wm * 32 + mt * 16 + l15][q8];
#pragma unroll
        for (int nt = 0; nt < 4; ++nt)
            bfr[nt] = *(const bf16x8*)&Bs[wn * 64 + nt * 16 + l15][q8];
#pragma unroll
        for (int mt = 0; mt < 2; ++mt)
#pragma unroll
            for (int nt = 0; nt < 4; ++nt)
                acc[mt][nt] = MFMA(af[mt], bfr[nt], acc[mt][nt]);
        __syncthreads();
    }

    ushort* xout = dir ? xb : xf;
#pragma unroll
    for (int mt = 0; mt < 2; ++mt) {
        int m = r * T_ + t0 + wm * 32 + mt * 16 + (lane >> 4) * 4;
#pragma unroll
        for (int nt = 0; nt < 4; ++nt) {
            int col = N0 + wn * 64 + nt * 16 + l15;
            float bv = bias[col];
#pragma unroll
            for (int rg = 0; rg < 4; ++rg)
                xout[(long)(m + rg) * G4 + col] = f2bf(acc[mt][nt][rg] + bv);
        }
    }
}

// ---------------------------------------------------------------------------
// K2 v5: PERSISTENT recurrence, barrier v3 (LLVM-memory-model-sanctioned).
// - h written with PLAIN cached stores.
// - arrival: tid0 RELEASE-stores the block's padded flag (compiler emits
//   buffer_wbl2 -> flushes this XCD's dirty h lines to the coherence point).
// - spin: RELAXED agent atomic loads only (coherent reads, NO invalidates —
//   round-4's 22us/step was acquire-in-loop = buffer_inv per poll).
// - after spin success: ONE ACQUIRE load per block (single buffer_inv), then
//   plain cached h reads are safe.
// - leader block 0 polls 255 flags with 255 parallel threads, publishes `go`.
// - Whh in registers (16 bf16x8/wave), c in 2 VGPRs/thread, As swizzled.
// Co-residency: 256 blocks, LDS 42.5KB -> 3 blocks/CU capacity; always fits.
// ---------------------------------------------------------------------------
__global__ __launch_bounds__(256) void k_recur(
    const ushort* __restrict__ xf, const ushort* __restrict__ xb,
    ushort* __restrict__ hfB, ushort* __restrict__ hbB,
    const ushort* __restrict__ WhhBf, const ushort* __restrict__ WhhBb,
    const float* __restrict__ s1_c0, const float* __restrict__ s2_c0,
    int* __restrict__ bar)
{
    const int bx = blockIdx.x;
    const int s  = bx >> 7;          // stream: 0 fwd, 1 bwd
    const int rb = (bx >> 5) & 3;    // row block of 32
    const int jb = bx & 31;          // j block of 16
    const int r0 = rb * 32, j0 = jb * 16;

    const ushort* xW  = s ? xb : xf;
    const ushort* Whh = s ? WhhBb : WhhBf;
    ushort* hB = s ? hbB : hfB;

    const int tid = threadIdx.x;
    const int lane = tid & 63;
    const int g = tid >> 6;          // wave = gate (i,f,g,o)
    const int l15 = lane & 15, q8 = (lane >> 4) * 8;

    __shared__ __align__(16) ushort As[32][520];   // 32 rows x 512 k, swizzled chunks
    __shared__ float Gs[4][32][18];                // gate pre-acts 32 x 16

    int* flags = bar;                // flags[bx*32], 128 B apart
    int* go    = bar + NB * 32;      // own line

    // Whh fragments resident in registers: wave g, cols j0+l15, K=512
    bf16x8 bfr[16];
    {
        const ushort* brow = &Whh[((long)g * H_ + j0 + l15) * H_];
#pragma unroll
        for (int ks = 0; ks < 16; ++ks)
            bfr[ks] = *(const bf16x8*)&brow[ks * 32 + q8];
    }

    // cell ownership: thread -> (row rr, j-pair jj)
    const int rr = tid >> 3, jj = (tid & 7) * 2;
    const int rg_ = r0 + rr;
    const int rl  = (rg_ < B_) ? rg_ : rg_ - B_;
    const float* c0p = (rg_ < B_) ? s1_c0 : s2_c0;   // [2][B][H]
    float c_0 = c0p[(long)s * B_ * H_ + (long)rl * H_ + j0 + jj];
    float c_1 = c0p[(long)s * B_ * H_ + (long)rl * H_ + j0 + jj + 1];

    // A staging: thread -> (row arow, chunk aseg); chunk placed at (aseg+arow)&7
    const int arow = tid >> 3, aseg = tid & 7;
    const int swz = ((aseg + arow) & 7) * 8;

    for (int t = 0; t < T_; ++t) {
        if (t) {
            __syncthreads();   // wave-level vmcnt drain: this block's h(t)
                               // stores are in its XCD L2 before arrival
            if (bx == 0) {
                if (tid > 0)
                    while (__hip_atomic_load(&flags[tid * 32], __ATOMIC_RELAXED,
                                             __HIP_MEMORY_SCOPE_AGENT) < t)
                        __builtin_amdgcn_s_sleep(2);
                __syncthreads();
                if (tid == 0) {
                    // release: wbl2 flushes leader's dirty h, then publish go
                    __hip_atomic_store(go, t, __ATOMIC_RELEASE,
                                       __HIP_MEMORY_SCOPE_AGENT);
                    // acquire: one buffer_inv so cached h reads are fresh
                    (void)__hip_atomic_load(&flags[32], __ATOMIC_ACQUIRE,
                                            __HIP_MEMORY_SCOPE_AGENT);
                }
                __syncthreads();
            } else {
                if (tid == 0) {
                    // release: wbl2 flushes this block's dirty h, then flag
                    __hip_atomic_store(&flags[bx * 32], t, __ATOMIC_RELEASE,
                                       __HIP_MEMORY_SCOPE_AGENT);
                    while (__hip_atomic_load(go, __ATOMIC_RELAXED,
                                             __HIP_MEMORY_SCOPE_AGENT) < t)
                        __builtin_amdgcn_s_sleep(2);
                    // acquire: one buffer_inv for this XCD
                    (void)__hip_atomic_load(go, __ATOMIC_ACQUIRE,
                                            __HIP_MEMORY_SCOPE_AGENT);
                }
                __syncthreads();
            }
        }

        // xW gate pre-activations (plain loads; read-only data)
        uint xw[4];
        const long xbase = ((long)rg_ * T_ + t) * G4 + j0 + jj;
#pragma unroll
        for (int gg = 0; gg < 4; ++gg)
            xw[gg] = *(const uint*)&xW[xbase + gg * H_];

        // h(t): plain cached reads (safe: post-acquire), 8 x 16B per thread
        uint4 av[8];
        const ushort* hrow = &hB[((long)(r0 + arow) * TS + t) * H_ + aseg * 8];
#pragma unroll
        for (int sl = 0; sl < 8; ++sl)
            av[sl] = *(const uint4*)&hrow[sl * 64];

#pragma unroll
        for (int sl = 0; sl < 8; ++sl)
            *(uint4*)&As[arow][sl * 64 + swz] = av[sl];
        __syncthreads();

        f32x4 acc0 = {}, acc1 = {};
#pragma unroll
        for (int ks = 0; ks < 16; ++ks) {
            const int e  = ks * 32 + q8;
            const int sl = e >> 6;
            const int c  = (e >> 3) & 7;
            bf16x8 a0 = *(const bf16x8*)&As[l15][sl * 64 + (((c + l15) & 7) << 3)];
            bf16x8 a1 = *(const bf16x8*)&As[16 + l15][sl * 64 + (((c + l15) & 7) << 3)];
            acc0 = MFMA(a0, bfr[ks], acc0);
            acc1 = MFMA(a1, bfr[ks], acc1);
        }

        // publish gate pre-acts (C layout: col=lane&15, row=(lane>>4)*4+rg)
#pragma unroll
        for (int rg2 = 0; rg2 < 4; ++rg2) {
            Gs[g][(lane >> 4) * 4 + rg2][l15]      = acc0[rg2];
            Gs[g][16 + (lane >> 4) * 4 + rg2][l15] = acc1[rg2];
        }
        __syncthreads();

        // fused cell update for 2 adjacent cells
        float gi0 = Gs[0][rr][jj]     + bf2f((ushort)(xw[0] & 0xffff));
        float gi1 = Gs[0][rr][jj + 1] + bf2f((ushort)(xw[0] >> 16));
        float gf0 = Gs[1][rr][jj]     + bf2f((ushort)(xw[1] & 0xffff));
        float gf1 = Gs[1][rr][jj + 1] + bf2f((ushort)(xw[1] >> 16));
        float gg0 = Gs[2][rr][jj]     + bf2f((ushort)(xw[2] & 0xffff));
        float gg1 = Gs[2][rr][jj + 1] + bf2f((ushort)(xw[2] >> 16));
        float go0 = Gs[3][rr][jj]     + bf2f((ushort)(xw[3] & 0xffff));
        float go1 = Gs[3][rr][jj + 1] + bf2f((ushort)(xw[3] >> 16));

        c_0 = fsig(gf0) * c_0 + fsig(gi0) * ftanh(gg0);
        c_1 = fsig(gf1) * c_1 + fsig(gi1) * ftanh(gg1);
        float h0 = fsig(go0) * ftanh(c_0);
        float h1 = fsig(go1) * ftanh(c_1);

        uint hp = (uint)f2bf(h0) | ((uint)f2bf(h1) << 16);
        // plain cached store; made visible by next barrier's release (wbl2)
        *(uint*)&hB[((long)rg_ * TS + t + 1) * H_ + j0 + jj] = hp;
    }
}

// ---------------------------------------------------------------------------
// K3a: U[m,c] = tanh(Hout[m,:] @ S1W^T) via bf16 MFMA (unchanged).
// ---------------------------------------------------------------------------
__global__ __launch_bounds__(256) void k_attn_mfma(
    const ushort* __restrict__ hfB, const ushort* __restrict__ hbB,
    const int* __restrict__ l1, const int* __restrict__ l2,
    const ushort* __restrict__ S1WB, float* __restrict__ U)
{
    const int r  = blockIdx.y >> 1;
    const int t0 = (blockIdx.y & 1) * 64;
    const int N0 = blockIdx.x * 64;
    const int L  = (r < B_) ? l1[r] : l2[r - B_];
    if (L <= t0) return;

    const int tid = threadIdx.x;
    const int lane = tid & 63, w = tid >> 6;
    const int wm = w & 1, wn = w >> 1;
    const int l15 = lane & 15, q8 = (lane >> 4) * 8;

    __shared__ __align__(16) ushort As[64][72];
    __shared__ __align__(16) ushort Bs[64][72];

    f32x4 acc[2][2] = {};

    for (int k0 = 0; k0 < 2 * H_; k0 += 64) {
#pragma unroll
        for (int p = 0; p < 2; ++p) {   // A: 64 rows x 64 k
            int u = tid + p * 256;
            int row = u >> 3, seg = u & 7;
            int tpos = t0 + row;
            int k = k0 + seg * 8;
            long idx;
            const ushort* src;
            if (k0 < H_) {
                src = hfB; idx = ((long)r * TS + tpos + 1) * H_ + k;
            } else {
                int tt = (tpos < L) ? (L - 1 - tpos) : tpos;
                src = hbB; idx = ((long)r * TS + tt + 1) * H_ + (k - H_);
            }
            *(uint4*)&As[row][seg * 8] = *(const uint4*)&src[idx];
        }
#pragma unroll
        for (int p = 0; p < 2; ++p) {   // B: 64 cols x 64 k
            int u = tid + p * 256;
            int row = u >> 3, seg = u & 7;
            *(uint4*)&Bs[row][seg * 8] =
                *(const uint4*)&S1WB[(long)(N0 + row) * (2 * H_) + k0 + seg * 8];
        }
        __syncthreads();
#pragma unroll
        for (int ks = 0; ks < 2; ++ks) {
            bf16x8 a0 = *(const bf16x8*)&As[wm * 32 + l15][ks * 32 + q8];
            bf16x8 a1 = *(const bf16x8*)&As[wm * 32 + 16 + l15][ks * 32 + q8];
            bf16x8 b0 = *(const bf16x8*)&Bs[wn * 32 + l15][ks * 32 + q8];
            bf16x8 b1 = *(const bf16x8*)&Bs[wn * 32 + 16 + l15][ks * 32 + q8];
            acc[0][0] = MFMA(a0, b0, acc[0][0]);
            acc[0][1] = MFMA(a0, b1, acc[0][1]);
            acc[1][0] = MFMA(a1, b0, acc[1][0]);
            acc[1][1] = MFMA(a1, b1, acc[1][1]);
        }
        __syncthreads();
    }
#pragma unroll
    for (int mt = 0; mt < 2; ++mt) {
        int m = r * T_ + t0 + wm * 32 + mt * 16 + (lane >> 4) * 4;
#pragma unroll
        for (int nt = 0; nt < 2; ++nt) {
            int col = N0 + wn * 32 + nt * 16 + l15;
#pragma unroll
            for (int rg = 0; rg < 4; ++rg)
                U[(long)(m + rg) * C_ + col] = ftanh(acc[mt][nt][rg]);
        }
    }
}

// ---------------------------------------------------------------------------
// K3b: scores = U@S2W, masked softmax, pooled = attn @ Hout (unchanged).
// ---------------------------------------------------------------------------
__global__ __launch_bounds__(256) void k_attn_pool(
    const ushort* __restrict__ hfB, const ushort* __restrict__ hbB,
    const float* __restrict__ U, const float* __restrict__ S2W,
    const int* __restrict__ l1, const int* __restrict__ l2,
    float* __restrict__ pooled)
{
    const int r = blockIdx.x;
    const int L = (r < B_) ? l1[r] : l2[r - B_];
    const int tid = threadIdx.x;
    const int lane = tid & 63, w = tid >> 6;

    __shared__ float att[T_];

    for (int tt = w; tt < T_; tt += 4) {
        float p = 0.0f;
        if (tt < L) {
            const float* u = &U[(long)(r * T_ + tt) * C_];
            p = u[lane] * S2W[lane] + u[lane + 64] * S2W[lane + 64]
              + u[lane + 128] * S2W[lane + 128] + u[lane + 192] * S2W[lane + 192];
            for (int off = 32; off; off >>= 1) p += __shfl_down(p, off);
        }
        if (lane == 0) att[tt] = p;
    }
    __syncthreads();

    float mx = -1e30f;
    for (int tt = 0; tt < L; ++tt) mx = fmaxf(mx, att[tt]);
    __syncthreads();
    if (tid < T_) att[tid] = (tid < L) ? __expf(att[tid] - mx) : 0.0f;
    __syncthreads();
    float sum = 0.0f;
    for (int tt = 0; tt < L; ++tt) sum += att[tt];
    float inv = 1.0f / sum;

    for (int d = tid; d < 2 * H_; d += 256) {
        float a = 0.0f;
        for (int tt = 0; tt < L; ++tt) {
            float hv = (d < H_)
                ? bf2f(hfB[((long)r * TS + tt + 1) * H_ + d])
                : bf2f(hbB[((long)r * TS + (L - tt)) * H_ + (d - H_)]);
            a += att[tt] * hv;
        }
        pooled[(long)r * (2 * H_) + d] = a * inv;
    }
}

// ---------------------------------------------------------------------------
// K4a: om[b][mm] = merged[b] . mlpW[mm] + mlpb[mm] (unchanged).
// ---------------------------------------------------------------------------
__global__ __launch_bounds__(256) void k_mlp1(
    const float* __restrict__ pooled,
    const float* __restrict__ mlpW, const float* __restrict__ mlpb,
    float* __restrict__ om)
{
    const int mg = blockIdx.x;      // 0..7
    const int b  = blockIdx.y;      // 0..63
    const int tid = threadIdx.x;
    const int lane = tid & 63, w = tid >> 6;

    __shared__ __align__(16) float sm[2048];

#pragma unroll
    for (int it = 0; it < 8; ++it) {
        int d = tid + it * 256;
        float v;
        if (d < 1024) {
            v = pooled[(long)b * 1024 + d] + pooled[(long)(B_ + b) * 1024 + d];
        } else {
            int dd = d - 1024;
            float x = pooled[(long)b * 1024 + dd] - pooled[(long)(B_ + b) * 1024 + dd];
            v = x * x;
        }
        sm[d] = v;
    }
    __syncthreads();

    for (int i = 0; i < 16; ++i) {
        int mm = mg * 64 + w * 16 + i;
        const float* wrow = &mlpW[(long)mm * 2048];
        float ax = 0.f, ay = 0.f, az = 0.f, aw = 0.f;
#pragma unroll
        for (int it = 0; it < 8; ++it) {
            int k = it * 256 + lane * 4;
            float4 wv = *(const float4*)&wrow[k];
            float4 sv = *(const float4*)&sm[k];
            ax += wv.x * sv.x; ay += wv.y * sv.y;
            az += wv.z * sv.z; aw += wv.w * sv.w;
        }
        float ssum = (ax + ay) + (az + aw);
        for (int off = 32; off; off >>= 1) ssum += __shfl_down(ssum, off);
        if (lane == 0) om[(long)b * M_ + mm] = ssum + mlpb[mm];
    }
}

// K4b: out[b] = sigmoid(om[b] . outW + outb)   (CLS = 1)
__global__ __launch_bounds__(256) void k_final(
    const float* __restrict__ om,
    const float* __restrict__ outW, const float* __restrict__ outb,
    float* __restrict__ out)
{
    const int b = blockIdx.x;
    const int tid = threadIdx.x;
    __shared__ float red[256];
    float p = om[(long)b * M_ + tid] * outW[tid]
            + om[(long)b * M_ + 256 + tid] * outW[256 + tid];
    red[tid] = p;
    __syncthreads();
    for (int off = 128; off > 0; off >>= 1) {
        if (tid < off) red[tid] += red[tid + off];
        __syncthreads();
    }
    if (tid == 0) out[b] = 1.0f / (1.0f + __expf(-(red[0] + outb[0])));
}

// ---------------------------------------------------------------------------
extern "C" void kernel_launch(void* const* d_in, const int* in_sizes, int n_in,
                              void* d_out, int out_size, void* d_ws, size_t ws_size,
                              hipStream_t stream)
{
    const int*   s1    = (const int*)d_in[0];
    const int*   s2    = (const int*)d_in[1];
    const int*   l1    = (const int*)d_in[2];
    const int*   l2    = (const int*)d_in[3];
    const float* s1_h0 = (const float*)d_in[4];
    const float* s1_c0 = (const float*)d_in[5];
    const float* s2_h0 = (const float*)d_in[6];
    const float* s2_c0 = (const float*)d_in[7];
    const float* emb   = (const float*)d_in[8];
    const float* Wih_f = (const float*)d_in[9];
    const float* Whh_f = (const float*)d_in[10];
    const float* b_f   = (const float*)d_in[11];
    const float* Wih_b = (const float*)d_in[12];
    const float* Whh_b = (const float*)d_in[13];
    const float* b_b   = (const float*)d_in[14];
    const float* S1W   = (const float*)d_in[15];
    const float* S2W   = (const float*)d_in[16];
    const float* mlpW  = (const float*)d_in[17];
    const float* mlpb  = (const float*)d_in[18];
    const float* outW  = (const float*)d_in[19];
    const float* outb  = (const float*)d_in[20];
    float* out = (float*)d_out;

    // Workspace carve (all 16B-aligned)
    ushort* p16 = (ushort*)d_ws;
    ushort* embB  = p16;  p16 += (long)32000 * EP;
    ushort* WihBf = p16;  p16 += (long)G4 * EP;
    ushort* WihBb = p16;  p16 += (long)G4 * EP;
    ushort* WhhBf = p16;  p16 += (long)G4 * H_;
    ushort* WhhBb = p16;  p16 += (long)G4 * H_;
    ushort* S1WB  = p16;  p16 += (long)C_ * 2 * H_;
    ushort* xf    = p16;  p16 += (long)R_ * T_ * G4;
    ushort* xb    = p16;  p16 += (long)R_ * T_ * G4;
    ushort* hfB   = p16;  p16 += (long)R_ * TS * H_;
    ushort* hbB   = p16;  p16 += (long)R_ * TS * H_;
    float* pf = (float*)p16;
    float* U      = pf;   pf += (long)R_ * T_ * C_;
    float* pooled = pf;   pf += (long)R_ * 2 * H_;
    float* om     = pf;   pf += (long)B_ * M_;
    int*   bar    = (int*)pf;   // 64 KB barrier state: flags[bx*32], go at [NB*32]

    // barrier init (memset node; graph-capture-safe; re-zeroed every replay)
    hipMemsetAsync(bar, 0, 64 * 1024, stream);

    // P0/P1: weight conversion + state init
    k_cvt<<<32000, 256, 0, stream>>>(emb,   embB,  E_, EP);
    k_cvt<<<G4,    256, 0, stream>>>(Wih_f, WihBf, E_, EP);
    k_cvt<<<G4,    256, 0, stream>>>(Wih_b, WihBb, E_, EP);
    k_cvt<<<G4,    256, 0, stream>>>(Whh_f, WhhBf, H_, H_);
    k_cvt<<<G4,    256, 0, stream>>>(Whh_b, WhhBb, H_, H_);
    k_cvt<<<C_,    256, 0, stream>>>(S1W,   S1WB,  2 * H_, 2 * H_);
    k_init<<<R_, 256, 0, stream>>>(s1_h0, s2_h0, hfB, hbB);

    // K1: input GEMM
    k_embed_mfma<<<dim3(16, 256, 2), 256, 0, stream>>>(
        s1, s2, l1, l2, embB, WihBf, WihBb, b_f, b_b, xf, xb);

    // K2: full recurrence in ONE persistent launch
    k_recur<<<NB, 256, 0, stream>>>(xf, xb, hfB, hbB, WhhBf, WhhBb,
                                    s1_c0, s2_c0, bar);

    // K3: attention pooling
    k_attn_mfma<<<dim3(4, 256), 256, 0, stream>>>(hfB, hbB, l1, l2, S1WB, U);
    k_attn_pool<<<R_, 256, 0, stream>>>(hfB, hbB, U, S2W, l1, l2, pooled);

    // K4: MLP head
    k_mlp1<<<dim3(8, B_), 256, 0, stream>>>(pooled, mlpW, mlpb, om);
    k_final<<<B_, 256, 0, stream>>>(om, outW, outb, out);
}

// Round 7
// 841.317 us; speedup vs baseline: 3.7880x; 2.2067x over previous
//
#include <hip/hip_runtime.h>
#include <hip/hip_bf16.h>

// Problem constants (fixed by the reference)
#define B_  64
#define T_  128
#define E_  300
#define EP  320     // E padded to multiple of 32 for MFMA K-loop
#define H_  512
#define G4  2048    // 4*H
#define R_  128     // 2*B (s1+s2 batched; shared LSTM weights)
#define C_  256
#define M_  512
#define TS  (T_ + 1)  // h time slots: slot 0 = h0, slot t+1 = h(t)
#define NB  256     // persistent-kernel grid size

typedef short bf16x8 __attribute__((ext_vector_type(8)));
typedef float f32x4  __attribute__((ext_vector_type(4)));
#define MFMA(a, b, c) __builtin_amdgcn_mfma_f32_16x16x32_bf16((a), (b), (c), 0, 0, 0)

__device__ __forceinline__ float fsig(float x) { return 1.0f / (1.0f + __expf(-x)); }
__device__ __forceinline__ float ftanh(float x) {
    float a = fminf(fabsf(x), 15.0f);
    float e = __expf(2.0f * a);
    return copysignf((e - 1.0f) / (e + 1.0f), x);
}
__device__ __forceinline__ ushort f2bf(float f) {
    __hip_bfloat16 h = __float2bfloat16(f);
    return *reinterpret_cast<ushort*>(&h);
}
__device__ __forceinline__ float bf2f(ushort u) {
    __hip_bfloat16 h = *reinterpret_cast<__hip_bfloat16*>(&u);
    return __bfloat162float(h);
}

// ---------------------------------------------------------------------------
// P0: f32 -> bf16 row-wise convert with K padding (zeros in [sk, dk)).
// ---------------------------------------------------------------------------
__global__ __launch_bounds__(256) void k_cvt(const float* __restrict__ src,
                                             ushort* __restrict__ dst,
                                             int sk, int dk)
{
    const int r = blockIdx.x;
    for (int c = threadIdx.x; c < dk; c += 256)
        dst[(long)r * dk + c] = (c < sk) ? f2bf(src[(long)r * sk + c]) : (ushort)0;
}

// P1: init h slot 0 (bf16) from the h0 inputs.
__global__ __launch_bounds__(256) void k_init(
    const float* __restrict__ s1_h0, const float* __restrict__ s2_h0,
    ushort* __restrict__ hfB, ushort* __restrict__ hbB)
{
    const int r = blockIdx.x;                    // 0..127
    const int rl = (r < B_) ? r : r - B_;
    const float* h0 = (r < B_) ? s1_h0 : s2_h0;  // [2][B][H]
    for (int j = threadIdx.x; j < H_; j += 256) {
        hfB[(long)r * TS * H_ + j] = f2bf(h0[(long)0 * B_ * H_ + (long)rl * H_ + j]);
        hbB[(long)r * TS * H_ + j] = f2bf(h0[(long)1 * B_ * H_ + (long)rl * H_ + j]);
    }
}

// ---------------------------------------------------------------------------
// K1: embedding gather + input GEMM via bf16 MFMA (unchanged).
// ---------------------------------------------------------------------------
__global__ __launch_bounds__(256) void k_embed_mfma(
    const int* __restrict__ s1, const int* __restrict__ s2,
    const int* __restrict__ l1, const int* __restrict__ l2,
    const ushort* __restrict__ embB,
    const ushort* __restrict__ WihBf, const ushort* __restrict__ WihBb,
    const float* __restrict__ b_f, const float* __restrict__ b_b,
    ushort* __restrict__ xf, ushort* __restrict__ xb)
{
    const int dir = blockIdx.z;
    const int r   = blockIdx.y >> 1;
    const int t0  = (blockIdx.y & 1) * 64;
    const int N0  = blockIdx.x * 128;
    const int L   = (r < B_) ? l1[r] : l2[r - B_];
    if (L <= t0) return;

    const int tid = threadIdx.x;
    const int lane = tid & 63, w = tid >> 6;
    const int wm = w & 1, wn = w >> 1;
    const int l15 = lane & 15, q8 = (lane >> 4) * 8;

    __shared__ int toks[64];
    __shared__ __align__(16) ushort As[64][40];
    __shared__ __align__(16) ushort Bs[128][40];

    if (tid < 64) {
        int t  = t0 + tid;
        int tt = dir ? ((t < L) ? (L - 1 - t) : t) : t;
        toks[tid] = (r < B_) ? s1[r * T_ + tt] : s2[(r - B_) * T_ + tt];
    }
    __syncthreads();

    const ushort* Wih  = dir ? WihBb : WihBf;
    const float*  bias = dir ? b_b : b_f;

    f32x4 acc[2][4] = {};

    for (int k0 = 0; k0 < EP; k0 += 32) {
        {   // A: 64 rows x 32 k
            int row = tid >> 2, seg = tid & 3;
            *(uint4*)&As[row][seg * 8] =
                *(const uint4*)&embB[(long)toks[row] * EP + k0 + seg * 8];
        }
#pragma unroll
        for (int p = 0; p < 2; ++p) {   // B: 128 cols x 32 k
            int u = tid + p * 256;
            int row = u >> 2, seg = u & 3;
            *(uint4*)&Bs[row][seg * 8] =
                *(const uint4*)&Wih[(long)(N0 + row) * EP + k0 + seg * 8];
        }
        __syncthreads();
        bf16x8 af[2], bfr[4];
#pragma unroll
        for (int mt = 0; mt < 2; ++mt)
            af[mt] = *(const bf16x8*)&As[wm * 32 + mt * 16 + l15][q8];
#pragma unroll
        for (int nt = 0; nt < 4; ++nt)
            bfr[nt] = *(const bf16x8*)&Bs[wn * 64 + nt * 16 + l15][q8];
#pragma unroll
        for (int mt = 0; mt < 2; ++mt)
#pragma unroll
            for (int nt = 0; nt < 4; ++nt)
                acc[mt][nt] = MFMA(af[mt], bfr[nt], acc[mt][nt]);
        __syncthreads();
    }

    ushort* xout = dir ? xb : xf;
#pragma unroll
    for (int mt = 0; mt < 2; ++mt) {
        int m = r * T_ + t0 + wm * 32 + mt * 16 + (lane >> 4) * 4;
#pragma unroll
        for (int nt = 0; nt < 4; ++nt) {
            int col = N0 + wn * 64 + nt * 16 + l15;
            float bv = bias[col];
#pragma unroll
            for (int rg = 0; rg < 4; ++rg)
                xout[(long)(m + rg) * G4 + col] = f2bf(acc[mt][nt][rg] + bv);
        }
    }
}

// ---------------------------------------------------------------------------
// K2 v6: PERSISTENT recurrence, barrier v4 (group-local, all-to-all, no
// cache-maintenance ops).
// Dataflow fact: block (s,rb,jb) reads h(t) rows r0..r0+31 only, which are
// written exclusively by the 32 j-blocks of the SAME (s,rb) group => the
// barrier is 8 independent 32-block barriers, not one 256-block barrier.
// - h writes: relaxed agent atomic stores (write-through; round-4-proven).
// - h reads:  relaxed agent atomic 8B loads (coherence-point reads; the
//   compiler-correct version of round-5's asm). NO acquire/release anywhere
//   => no buffer_inv/wbl2 => xW stays L2-cached (round-6's 11.6us/step was
//   leader double-hop + per-block-per-step L2 invalidate).
// - visibility: __syncthreads drains vmcnt (h stores ack'd at the coherence
//   point) before tid0's flag store issues; pollers then read h from L3.
// - xW loads issued BEFORE the spin so their latency hides under the wait.
// Co-residency: 256 blocks, LDS 42.5KB -> 3 blocks/CU; always fits (and
// group-local barriers can't deadlock even under partial residency).
// ---------------------------------------------------------------------------
__global__ __launch_bounds__(256) void k_recur(
    const ushort* __restrict__ xf, const ushort* __restrict__ xb,
    ushort* __restrict__ hfB, ushort* __restrict__ hbB,
    const ushort* __restrict__ WhhBf, const ushort* __restrict__ WhhBb,
    const float* __restrict__ s1_c0, const float* __restrict__ s2_c0,
    int* __restrict__ bar)
{
    const int bx = blockIdx.x;
    const int s  = bx >> 7;          // stream: 0 fwd, 1 bwd
    const int rb = (bx >> 5) & 3;    // row block of 32
    const int jb = bx & 31;          // j block of 16
    const int r0 = rb * 32, j0 = jb * 16;
    const int grp0 = bx & ~31;       // first block of this (s,rb) group

    const ushort* xW  = s ? xb : xf;
    const ushort* Whh = s ? WhhBb : WhhBf;
    ushort* hB = s ? hbB : hfB;

    const int tid = threadIdx.x;
    const int lane = tid & 63;
    const int g = tid >> 6;          // wave = gate (i,f,g,o)
    const int l15 = lane & 15, q8 = (lane >> 4) * 8;

    __shared__ __align__(16) ushort As[32][520];   // 32 rows x 512 k, swizzled chunks
    __shared__ float Gs[4][32][18];                // gate pre-acts 32 x 16

    int* flags = bar;                // flags[bx*32], 128 B apart

    // Whh fragments resident in registers: wave g, cols j0+l15, K=512
    bf16x8 bfr[16];
    {
        const ushort* brow = &Whh[((long)g * H_ + j0 + l15) * H_];
#pragma unroll
        for (int ks = 0; ks < 16; ++ks)
            bfr[ks] = *(const bf16x8*)&brow[ks * 32 + q8];
    }

    // cell ownership: thread -> (row rr, j-pair jj)
    const int rr = tid >> 3, jj = (tid & 7) * 2;
    const int rg_ = r0 + rr;
    const int rl  = (rg_ < B_) ? rg_ : rg_ - B_;
    const float* c0p = (rg_ < B_) ? s1_c0 : s2_c0;   // [2][B][H]
    float c_0 = c0p[(long)s * B_ * H_ + (long)rl * H_ + j0 + jj];
    float c_1 = c0p[(long)s * B_ * H_ + (long)rl * H_ + j0 + jj + 1];

    // A staging: thread -> (row arow, chunk aseg); chunk placed at (aseg+arow)&7
    const int arow = tid >> 3, aseg = tid & 7;
    const int swz = ((aseg + arow) & 7) * 8;

    for (int t = 0; t < T_; ++t) {
        // xW gate pre-activations for this step (plain cached loads, no
        // dependence on h(t)) — issued before the wait to hide latency
        uint xw[4];
        const long xbase = ((long)rg_ * T_ + t) * G4 + j0 + jj;
#pragma unroll
        for (int gg = 0; gg < 4; ++gg)
            xw[gg] = *(const uint*)&xW[xbase + gg * H_];

        if (t) {
            __syncthreads();   // each wave drains vmcnt before s_barrier =>
                               // this block's h(t) stores are ack'd at L3
            if (tid == 0)      // announce: this block finished step t-1
                __hip_atomic_store(&flags[bx * 32], t, __ATOMIC_RELAXED,
                                   __HIP_MEMORY_SCOPE_AGENT);
            if (tid < 32)      // wait for all 32 blocks of own group
                while (__hip_atomic_load(&flags[(grp0 + tid) * 32],
                                         __ATOMIC_RELAXED,
                                         __HIP_MEMORY_SCOPE_AGENT) < t)
                    __builtin_amdgcn_s_sleep(1);
            __syncthreads();
        }

        // h(t): coherence-point reads (relaxed agent 8B atomics), 8x16B/thread
        const ushort* hrow = &hB[((long)(r0 + arow) * TS + t) * H_ + aseg * 8];
        uint4 av[8];
#pragma unroll
        for (int sl = 0; sl < 8; ++sl) {
            const unsigned long long* p8 =
                (const unsigned long long*)(hrow + sl * 64);
            unsigned long long lo = __hip_atomic_load(p8, __ATOMIC_RELAXED,
                                                      __HIP_MEMORY_SCOPE_AGENT);
            unsigned long long hi = __hip_atomic_load(p8 + 1, __ATOMIC_RELAXED,
                                                      __HIP_MEMORY_SCOPE_AGENT);
            av[sl].x = (uint)lo; av[sl].y = (uint)(lo >> 32);
            av[sl].z = (uint)hi; av[sl].w = (uint)(hi >> 32);
        }

#pragma unroll
        for (int sl = 0; sl < 8; ++sl)
            *(uint4*)&As[arow][sl * 64 + swz] = av[sl];
        __syncthreads();

        f32x4 acc0 = {}, acc1 = {};
#pragma unroll
        for (int ks = 0; ks < 16; ++ks) {
            const int e  = ks * 32 + q8;
            const int sl = e >> 6;
            const int c  = (e >> 3) & 7;
            bf16x8 a0 = *(const bf16x8*)&As[l15][sl * 64 + (((c + l15) & 7) << 3)];
            bf16x8 a1 = *(const bf16x8*)&As[16 + l15][sl * 64 + (((c + l15) & 7) << 3)];
            acc0 = MFMA(a0, bfr[ks], acc0);
            acc1 = MFMA(a1, bfr[ks], acc1);
        }

        // publish gate pre-acts (C layout: col=lane&15, row=(lane>>4)*4+rg)
#pragma unroll
        for (int rg2 = 0; rg2 < 4; ++rg2) {
            Gs[g][(lane >> 4) * 4 + rg2][l15]      = acc0[rg2];
            Gs[g][16 + (lane >> 4) * 4 + rg2][l15] = acc1[rg2];
        }
        __syncthreads();

        // fused cell update for 2 adjacent cells
        float gi0 = Gs[0][rr][jj]     + bf2f((ushort)(xw[0] & 0xffff));
        float gi1 = Gs[0][rr][jj + 1] + bf2f((ushort)(xw[0] >> 16));
        float gf0 = Gs[1][rr][jj]     + bf2f((ushort)(xw[1] & 0xffff));
        float gf1 = Gs[1][rr][jj + 1] + bf2f((ushort)(xw[1] >> 16));
        float gg0 = Gs[2][rr][jj]     + bf2f((ushort)(xw[2] & 0xffff));
        float gg1 = Gs[2][rr][jj + 1] + bf2f((ushort)(xw[2] >> 16));
        float go0 = Gs[3][rr][jj]     + bf2f((ushort)(xw[3] & 0xffff));
        float go1 = Gs[3][rr][jj + 1] + bf2f((ushort)(xw[3] >> 16));

        c_0 = fsig(gf0) * c_0 + fsig(gi0) * ftanh(gg0);
        c_1 = fsig(gf1) * c_1 + fsig(gi1) * ftanh(gg1);
        float h0 = fsig(go0) * ftanh(c_0);
        float h1 = fsig(go1) * ftanh(c_1);

        uint hp = (uint)f2bf(h0) | ((uint)f2bf(h1) << 16);
        // relaxed agent write-through: lands at the coherence point; ack'd
        // (vmcnt) before the next barrier's flag store can issue
        __hip_atomic_store((uint*)&hB[((long)rg_ * TS + t + 1) * H_ + j0 + jj],
                           hp, __ATOMIC_RELAXED, __HIP_MEMORY_SCOPE_AGENT);
    }
}

// ---------------------------------------------------------------------------
// K3a: U[m,c] = tanh(Hout[m,:] @ S1W^T) via bf16 MFMA (unchanged).
// ---------------------------------------------------------------------------
__global__ __launch_bounds__(256) void k_attn_mfma(
    const ushort* __restrict__ hfB, const ushort* __restrict__ hbB,
    const int* __restrict__ l1, const int* __restrict__ l2,
    const ushort* __restrict__ S1WB, float* __restrict__ U)
{
    const int r  = blockIdx.y >> 1;
    const int t0 = (blockIdx.y & 1) * 64;
    const int N0 = blockIdx.x * 64;
    const int L  = (r < B_) ? l1[r] : l2[r - B_];
    if (L <= t0) return;

    const int tid = threadIdx.x;
    const int lane = tid & 63, w = tid >> 6;
    const int wm = w & 1, wn = w >> 1;
    const int l15 = lane & 15, q8 = (lane >> 4) * 8;

    __shared__ __align__(16) ushort As[64][72];
    __shared__ __align__(16) ushort Bs[64][72];

    f32x4 acc[2][2] = {};

    for (int k0 = 0; k0 < 2 * H_; k0 += 64) {
#pragma unroll
        for (int p = 0; p < 2; ++p) {   // A: 64 rows x 64 k
            int u = tid + p * 256;
            int row = u >> 3, seg = u & 7;
            int tpos = t0 + row;
            int k = k0 + seg * 8;
            long idx;
            const ushort* src;
            if (k0 < H_) {
                src = hfB; idx = ((long)r * TS + tpos + 1) * H_ + k;
            } else {
                int tt = (tpos < L) ? (L - 1 - tpos) : tpos;
                src = hbB; idx = ((long)r * TS + tt + 1) * H_ + (k - H_);
            }
            *(uint4*)&As[row][seg * 8] = *(const uint4*)&src[idx];
        }
#pragma unroll
        for (int p = 0; p < 2; ++p) {   // B: 64 cols x 64 k
            int u = tid + p * 256;
            int row = u >> 3, seg = u & 7;
            *(uint4*)&Bs[row][seg * 8] =
                *(const uint4*)&S1WB[(long)(N0 + row) * (2 * H_) + k0 + seg * 8];
        }
        __syncthreads();
#pragma unroll
        for (int ks = 0; ks < 2; ++ks) {
            bf16x8 a0 = *(const bf16x8*)&As[wm * 32 + l15][ks * 32 + q8];
            bf16x8 a1 = *(const bf16x8*)&As[wm * 32 + 16 + l15][ks * 32 + q8];
            bf16x8 b0 = *(const bf16x8*)&Bs[wn * 32 + l15][ks * 32 + q8];
            bf16x8 b1 = *(const bf16x8*)&Bs[wn * 32 + 16 + l15][ks * 32 + q8];
            acc[0][0] = MFMA(a0, b0, acc[0][0]);
            acc[0][1] = MFMA(a0, b1, acc[0][1]);
            acc[1][0] = MFMA(a1, b0, acc[1][0]);
            acc[1][1] = MFMA(a1, b1, acc[1][1]);
        }
        __syncthreads();
    }
#pragma unroll
    for (int mt = 0; mt < 2; ++mt) {
        int m = r * T_ + t0 + wm * 32 + mt * 16 + (lane >> 4) * 4;
#pragma unroll
        for (int nt = 0; nt < 2; ++nt) {
            int col = N0 + wn * 32 + nt * 16 + l15;
#pragma unroll
            for (int rg = 0; rg < 4; ++rg)
                U[(long)(m + rg) * C_ + col] = ftanh(acc[mt][nt][rg]);
        }
    }
}

// ---------------------------------------------------------------------------
// K3b: scores = U@S2W, masked softmax, pooled = attn @ Hout (unchanged).
// ---------------------------------------------------------------------------
__global__ __launch_bounds__(256) void k_attn_pool(
    const ushort* __restrict__ hfB, const ushort* __restrict__ hbB,
    const float* __restrict__ U, const float* __restrict__ S2W,
    const int* __restrict__ l1, const int* __restrict__ l2,
    float* __restrict__ pooled)
{
    const int r = blockIdx.x;
    const int L = (r < B_) ? l1[r] : l2[r - B_];
    const int tid = threadIdx.x;
    const int lane = tid & 63, w = tid >> 6;

    __shared__ float att[T_];

    for (int tt = w; tt < T_; tt += 4) {
        float p = 0.0f;
        if (tt < L) {
            const float* u = &U[(long)(r * T_ + tt) * C_];
            p = u[lane] * S2W[lane] + u[lane + 64] * S2W[lane + 64]
              + u[lane + 128] * S2W[lane + 128] + u[lane + 192] * S2W[lane + 192];
            for (int off = 32; off; off >>= 1) p += __shfl_down(p, off);
        }
        if (lane == 0) att[tt] = p;
    }
    __syncthreads();

    float mx = -1e30f;
    for (int tt = 0; tt < L; ++tt) mx = fmaxf(mx, att[tt]);
    __syncthreads();
    if (tid < T_) att[tid] = (tid < L) ? __expf(att[tid] - mx) : 0.0f;
    __syncthreads();
    float sum = 0.0f;
    for (int tt = 0; tt < L; ++tt) sum += att[tt];
    float inv = 1.0f / sum;

    for (int d = tid; d < 2 * H_; d += 256) {
        float a = 0.0f;
        for (int tt = 0; tt < L; ++tt) {
            float hv = (d < H_)
                ? bf2f(hfB[((long)r * TS + tt + 1) * H_ + d])
                : bf2f(hbB[((long)r * TS + (L - tt)) * H_ + (d - H_)]);
            a += att[tt] * hv;
        }
        pooled[(long)r * (2 * H_) + d] = a * inv;
    }
}

// ---------------------------------------------------------------------------
// K4a: om[b][mm] = merged[b] . mlpW[mm] + mlpb[mm] (unchanged).
// ---------------------------------------------------------------------------
__global__ __launch_bounds__(256) void k_mlp1(
    const float* __restrict__ pooled,
    const float* __restrict__ mlpW, const float* __restrict__ mlpb,
    float* __restrict__ om)
{
    const int mg = blockIdx.x;      // 0..7
    const int b  = blockIdx.y;      // 0..63
    const int tid = threadIdx.x;
    const int lane = tid & 63, w = tid >> 6;

    __shared__ __align__(16) float sm[2048];

#pragma unroll
    for (int it = 0; it < 8; ++it) {
        int d = tid + it * 256;
        float v;
        if (d < 1024) {
            v = pooled[(long)b * 1024 + d] + pooled[(long)(B_ + b) * 1024 + d];
        } else {
            int dd = d - 1024;
            float x = pooled[(long)b * 1024 + dd] - pooled[(long)(B_ + b) * 1024 + dd];
            v = x * x;
        }
        sm[d] = v;
    }
    __syncthreads();

    for (int i = 0; i < 16; ++i) {
        int mm = mg * 64 + w * 16 + i;
        const float* wrow = &mlpW[(long)mm * 2048];
        float ax = 0.f, ay = 0.f, az = 0.f, aw = 0.f;
#pragma unroll
        for (int it = 0; it < 8; ++it) {
            int k = it * 256 + lane * 4;
            float4 wv = *(const float4*)&wrow[k];
            float4 sv = *(const float4*)&sm[k];
            ax += wv.x * sv.x; ay += wv.y * sv.y;
            az += wv.z * sv.z; aw += wv.w * sv.w;
        }
        float ssum = (ax + ay) + (az + aw);
        for (int off = 32; off; off >>= 1) ssum += __shfl_down(ssum, off);
        if (lane == 0) om[(long)b * M_ + mm] = ssum + mlpb[mm];
    }
}

// K4b: out[b] = sigmoid(om[b] . outW + outb)   (CLS = 1)
__global__ __launch_bounds__(256) void k_final(
    const float* __restrict__ om,
    const float* __restrict__ outW, const float* __restrict__ outb,
    float* __restrict__ out)
{
    const int b = blockIdx.x;
    const int tid = threadIdx.x;
    __shared__ float red[256];
    float p = om[(long)b * M_ + tid] * outW[tid]
            + om[(long)b * M_ + 256 + tid] * outW[256 + tid];
    red[tid] = p;
    __syncthreads();
    for (int off = 128; off > 0; off >>= 1) {
        if (tid < off) red[tid] += red[tid + off];
        __syncthreads();
    }
    if (tid == 0) out[b] = 1.0f / (1.0f + __expf(-(red[0] + outb[0])));
}

// ---------------------------------------------------------------------------
extern "C" void kernel_launch(void* const* d_in, const int* in_sizes, int n_in,
                              void* d_out, int out_size, void* d_ws, size_t ws_size,
                              hipStream_t stream)
{
    const int*   s1    = (const int*)d_in[0];
    const int*   s2    = (const int*)d_in[1];
    const int*   l1    = (const int*)d_in[2];
    const int*   l2    = (const int*)d_in[3];
    const float* s1_h0 = (const float*)d_in[4];
    const float* s1_c0 = (const float*)d_in[5];
    const float* s2_h0 = (const float*)d_in[6];
    const float* s2_c0 = (const float*)d_in[7];
    const float* emb   = (const float*)d_in[8];
    const float* Wih_f = (const float*)d_in[9];
    const float* Whh_f = (const float*)d_in[10];
    const float* b_f   = (const float*)d_in[11];
    const float* Wih_b = (const float*)d_in[12];
    const float* Whh_b = (const float*)d_in[13];
    const float* b_b   = (const float*)d_in[14];
    const float* S1W   = (const float*)d_in[15];
    const float* S2W   = (const float*)d_in[16];
    const float* mlpW  = (const float*)d_in[17];
    const float* mlpb  = (const float*)d_in[18];
    const float* outW  = (const float*)d_in[19];
    const float* outb  = (const float*)d_in[20];
    float* out = (float*)d_out;

    // Workspace carve (all 16B-aligned)
    ushort* p16 = (ushort*)d_ws;
    ushort* embB  = p16;  p16 += (long)32000 * EP;
    ushort* WihBf = p16;  p16 += (long)G4 * EP;
    ushort* WihBb = p16;  p16 += (long)G4 * EP;
    ushort* WhhBf = p16;  p16 += (long)G4 * H_;
    ushort* WhhBb = p16;  p16 += (long)G4 * H_;
    ushort* S1WB  = p16;  p16 += (long)C_ * 2 * H_;
    ushort* xf    = p16;  p16 += (long)R_ * T_ * G4;
    ushort* xb    = p16;  p16 += (long)R_ * T_ * G4;
    ushort* hfB   = p16;  p16 += (long)R_ * TS * H_;
    ushort* hbB   = p16;  p16 += (long)R_ * TS * H_;
    float* pf = (float*)p16;
    float* U      = pf;   pf += (long)R_ * T_ * C_;
    float* pooled = pf;   pf += (long)R_ * 2 * H_;
    float* om     = pf;   pf += (long)B_ * M_;
    int*   bar    = (int*)pf;   // 32 KB barrier state: flags[bx*32]

    // barrier init (memset node; graph-capture-safe; re-zeroed every replay)
    hipMemsetAsync(bar, 0, 64 * 1024, stream);

    // P0/P1: weight conversion + state init
    k_cvt<<<32000, 256, 0, stream>>>(emb,   embB,  E_, EP);
    k_cvt<<<G4,    256, 0, stream>>>(Wih_f, WihBf, E_, EP);
    k_cvt<<<G4,    256, 0, stream>>>(Wih_b, WihBb, E_, EP);
    k_cvt<<<G4,    256, 0, stream>>>(Whh_f, WhhBf, H_, H_);
    k_cvt<<<G4,    256, 0, stream>>>(Whh_b, WhhBb, H_, H_);
    k_cvt<<<C_,    256, 0, stream>>>(S1W,   S1WB,  2 * H_, 2 * H_);
    k_init<<<R_, 256, 0, stream>>>(s1_h0, s2_h0, hfB, hbB);

    // K1: input GEMM
    k_embed_mfma<<<dim3(16, 256, 2), 256, 0, stream>>>(
        s1, s2, l1, l2, embB, WihBf, WihBb, b_f, b_b, xf, xb);

    // K2: full recurrence in ONE persistent launch
    k_recur<<<NB, 256, 0, stream>>>(xf, xb, hfB, hbB, WhhBf, WhhBb,
                                    s1_c0, s2_c0, bar);

    // K3: attention pooling
    k_attn_mfma<<<dim3(4, 256), 256, 0, stream>>>(hfB, hbB, l1, l2, S1WB, U);
    k_attn_pool<<<R_, 256, 0, stream>>>(hfB, hbB, U, S2W, l1, l2, pooled);

    // K4: MLP head
    k_mlp1<<<dim3(8, B_), 256, 0, stream>>>(pooled, mlpW, mlpb, om);
    k_final<<<B_, 256, 0, stream>>>(om, outW, outb, out);
}

// Round 8
// 827.090 us; speedup vs baseline: 3.8532x; 1.0172x over previous
//
#include <hip/hip_runtime.h>
#include <hip/hip_bf16.h>

// Problem constants (fixed by the reference)
#define B_  64
#define T_  128
#define E_  300
#define EP  320     // E padded to multiple of 32 for MFMA K-loop
#define H_  512
#define G4  2048    // 4*H
#define R_  128     // 2*B (s1+s2 batched; shared LSTM weights)
#define C_  256
#define M_  512
#define TS  (T_ + 1)  // h time slots: slot 0 = h0, slot t+1 = h(t)
#define NB  128     // persistent-kernel grid: 2 streams x 4 rowblocks x 16 jblocks

typedef short bf16x8 __attribute__((ext_vector_type(8)));
typedef float f32x4  __attribute__((ext_vector_type(4)));
#define MFMA(a, b, c) __builtin_amdgcn_mfma_f32_16x16x32_bf16((a), (b), (c), 0, 0, 0)

__device__ __forceinline__ float fsig(float x) { return 1.0f / (1.0f + __expf(-x)); }
__device__ __forceinline__ float ftanh(float x) {
    float a = fminf(fabsf(x), 15.0f);
    float e = __expf(2.0f * a);
    return copysignf((e - 1.0f) / (e + 1.0f), x);
}
__device__ __forceinline__ ushort f2bf(float f) {
    __hip_bfloat16 h = __float2bfloat16(f);
    return *reinterpret_cast<ushort*>(&h);
}
__device__ __forceinline__ float bf2f(ushort u) {
    __hip_bfloat16 h = *reinterpret_cast<__hip_bfloat16*>(&u);
    return __bfloat162float(h);
}

// ---------------------------------------------------------------------------
// P0: fused f32 -> bf16 conversion for ALL weight tensors (one launch).
// Region table resolved by blockIdx range; K-padding zeros in [sk, dk).
// ---------------------------------------------------------------------------
__global__ __launch_bounds__(256) void k_cvt_all(
    const float* __restrict__ emb,
    const float* __restrict__ Wih_f, const float* __restrict__ Wih_b,
    const float* __restrict__ Whh_f, const float* __restrict__ Whh_b,
    const float* __restrict__ S1W,
    ushort* __restrict__ embB,
    ushort* __restrict__ WihBf, ushort* __restrict__ WihBb,
    ushort* __restrict__ WhhBf, ushort* __restrict__ WhhBb,
    ushort* __restrict__ S1WB)
{
    int b = blockIdx.x;
    const float* src; ushort* dst; int r, sk, dk;
    if (b < 32000)      { src = emb;   dst = embB;  r = b;          sk = E_;    dk = EP; }
    else if (b < 34048) { src = Wih_f; dst = WihBf; r = b - 32000;  sk = E_;    dk = EP; }
    else if (b < 36096) { src = Wih_b; dst = WihBb; r = b - 34048;  sk = E_;    dk = EP; }
    else if (b < 38144) { src = Whh_f; dst = WhhBf; r = b - 36096;  sk = H_;    dk = H_; }
    else if (b < 40192) { src = Whh_b; dst = WhhBb; r = b - 38144;  sk = H_;    dk = H_; }
    else                { src = S1W;   dst = S1WB;  r = b - 40192;  sk = 2*H_;  dk = 2*H_; }
    for (int c = threadIdx.x; c < dk; c += 256)
        dst[(long)r * dk + c] = (c < sk) ? f2bf(src[(long)r * sk + c]) : (ushort)0;
}

// P1: init h slot 0 (bf16) from the h0 inputs.
__global__ __launch_bounds__(256) void k_init(
    const float* __restrict__ s1_h0, const float* __restrict__ s2_h0,
    ushort* __restrict__ hfB, ushort* __restrict__ hbB)
{
    const int r = blockIdx.x;                    // 0..127
    const int rl = (r < B_) ? r : r - B_;
    const float* h0 = (r < B_) ? s1_h0 : s2_h0;  // [2][B][H]
    for (int j = threadIdx.x; j < H_; j += 256) {
        hfB[(long)r * TS * H_ + j] = f2bf(h0[(long)0 * B_ * H_ + (long)rl * H_ + j]);
        hbB[(long)r * TS * H_ + j] = f2bf(h0[(long)1 * B_ * H_ + (long)rl * H_ + j]);
    }
}

// ---------------------------------------------------------------------------
// K1: embedding gather + input GEMM via bf16 MFMA (unchanged).
// ---------------------------------------------------------------------------
__global__ __launch_bounds__(256) void k_embed_mfma(
    const int* __restrict__ s1, const int* __restrict__ s2,
    const int* __restrict__ l1, const int* __restrict__ l2,
    const ushort* __restrict__ embB,
    const ushort* __restrict__ WihBf, const ushort* __restrict__ WihBb,
    const float* __restrict__ b_f, const float* __restrict__ b_b,
    ushort* __restrict__ xf, ushort* __restrict__ xb)
{
    const int dir = blockIdx.z;
    const int r   = blockIdx.y >> 1;
    const int t0  = (blockIdx.y & 1) * 64;
    const int N0  = blockIdx.x * 128;
    const int L   = (r < B_) ? l1[r] : l2[r - B_];
    if (L <= t0) return;

    const int tid = threadIdx.x;
    const int lane = tid & 63, w = tid >> 6;
    const int wm = w & 1, wn = w >> 1;
    const int l15 = lane & 15, q8 = (lane >> 4) * 8;

    __shared__ int toks[64];
    __shared__ __align__(16) ushort As[64][40];
    __shared__ __align__(16) ushort Bs[128][40];

    if (tid < 64) {
        int t  = t0 + tid;
        int tt = dir ? ((t < L) ? (L - 1 - t) : t) : t;
        toks[tid] = (r < B_) ? s1[r * T_ + tt] : s2[(r - B_) * T_ + tt];
    }
    __syncthreads();

    const ushort* Wih  = dir ? WihBb : WihBf;
    const float*  bias = dir ? b_b : b_f;

    f32x4 acc[2][4] = {};

    for (int k0 = 0; k0 < EP; k0 += 32) {
        {   // A: 64 rows x 32 k
            int row = tid >> 2, seg = tid & 3;
            *(uint4*)&As[row][seg * 8] =
                *(const uint4*)&embB[(long)toks[row] * EP + k0 + seg * 8];
        }
#pragma unroll
        for (int p = 0; p < 2; ++p) {   // B: 128 cols x 32 k
            int u = tid + p * 256;
            int row = u >> 2, seg = u & 3;
            *(uint4*)&Bs[row][seg * 8] =
                *(const uint4*)&Wih[(long)(N0 + row) * EP + k0 + seg * 8];
        }
        __syncthreads();
        bf16x8 af[2], bfr[4];
#pragma unroll
        for (int mt = 0; mt < 2; ++mt)
            af[mt] = *(const bf16x8*)&As[wm * 32 + mt * 16 + l15][q8];
#pragma unroll
        for (int nt = 0; nt < 4; ++nt)
            bfr[nt] = *(const bf16x8*)&Bs[wn * 64 + nt * 16 + l15][q8];
#pragma unroll
        for (int mt = 0; mt < 2; ++mt)
#pragma unroll
            for (int nt = 0; nt < 4; ++nt)
                acc[mt][nt] = MFMA(af[mt], bfr[nt], acc[mt][nt]);
        __syncthreads();
    }

    ushort* xout = dir ? xb : xf;
#pragma unroll
    for (int mt = 0; mt < 2; ++mt) {
        int m = r * T_ + t0 + wm * 32 + mt * 16 + (lane >> 4) * 4;
#pragma unroll
        for (int nt = 0; nt < 4; ++nt) {
            int col = N0 + wn * 64 + nt * 16 + l15;
            float bv = bias[col];
#pragma unroll
            for (int rg = 0; rg < 4; ++rg)
                xout[(long)(m + rg) * G4 + col] = f2bf(acc[mt][nt][rg] + bv);
        }
    }
}

// ---------------------------------------------------------------------------
// K2 v7: PERSISTENT recurrence, 128 blocks (j-width 32).
// Geometry change vs v6 (which measured 3.65us/step at 256 blocks): each
// block owns 32 j-cols -> groups of 16 blocks (half the barrier width), and
// the per-step h broadcast halves (each consumer still reads its 32 rows x
// 512 = 32KB, but there are half as many consumers). Per-CU compute rises
// to 256 MFMAs (~0.5us) which stays far below the protocol cost.
// Protocol identical to the round-7-proven one: relaxed-only atomics, h
// write-through via relaxed agent stores, h read via relaxed agent 8B loads,
// group-local all-to-all flags. No cache-maintenance ops anywhere.
// ---------------------------------------------------------------------------
__global__ __launch_bounds__(256) void k_recur(
    const ushort* __restrict__ xf, const ushort* __restrict__ xb,
    ushort* __restrict__ hfB, ushort* __restrict__ hbB,
    const ushort* __restrict__ WhhBf, const ushort* __restrict__ WhhBb,
    const float* __restrict__ s1_c0, const float* __restrict__ s2_c0,
    int* __restrict__ bar)
{
    const int bx = blockIdx.x;
    const int s  = bx >> 6;          // stream: 0 fwd, 1 bwd
    const int rb = (bx >> 4) & 3;    // row block of 32
    const int jb = bx & 15;          // j block of 32
    const int r0 = rb * 32, j0 = jb * 32;
    const int grp0 = bx & ~15;       // first block of this (s,rb) group

    const ushort* xW  = s ? xb : xf;
    const ushort* Whh = s ? WhhBb : WhhBf;
    ushort* hB = s ? hbB : hfB;

    const int tid = threadIdx.x;
    const int lane = tid & 63;
    const int g = tid >> 6;          // wave = gate (i,f,g,o)
    const int l15 = lane & 15, q8 = (lane >> 4) * 8;

    __shared__ __align__(16) ushort As[32][520];   // 32 rows x 512 k, swizzled chunks
    __shared__ float Gs[4][32][33];                // gate pre-acts 32 x 32

    int* flags = bar;                // flags[bx*32], 128 B apart

    // Whh fragments resident in registers: wave g, 32 cols (2 n-tiles), K=512
    bf16x8 bfr[2][16];
#pragma unroll
    for (int nt = 0; nt < 2; ++nt) {
        const ushort* brow = &Whh[((long)g * H_ + j0 + nt * 16 + l15) * H_];
#pragma unroll
        for (int ks = 0; ks < 16; ++ks)
            bfr[nt][ks] = *(const bf16x8*)&brow[ks * 32 + q8];
    }

    // cell ownership: thread -> (row rr, 4 cols at jj)
    const int rr = tid >> 3, jj = (tid & 7) * 4;
    const int rg_ = r0 + rr;
    const int rl  = (rg_ < B_) ? rg_ : rg_ - B_;
    const float* c0p = (rg_ < B_) ? s1_c0 : s2_c0;   // [2][B][H]
    float cst[4];
#pragma unroll
    for (int cc = 0; cc < 4; ++cc)
        cst[cc] = c0p[(long)s * B_ * H_ + (long)rl * H_ + j0 + jj + cc];

    // A staging: thread -> (row arow, chunk aseg); chunk placed at (aseg+arow)&7
    const int arow = tid >> 3, aseg = tid & 7;
    const int swz = ((aseg + arow) & 7) * 8;

    for (int t = 0; t < T_; ++t) {
        // xW gate pre-activations for this step (4 cols x 4 gates), issued
        // before the wait so their latency hides under the barrier
        uint2 xw[4];
        const long xbase = ((long)rg_ * T_ + t) * G4 + j0 + jj;
#pragma unroll
        for (int gg = 0; gg < 4; ++gg)
            xw[gg] = *(const uint2*)&xW[xbase + gg * H_];

        if (t) {
            __syncthreads();   // wave-level vmcnt drain: this block's h(t)
                               // stores are ack'd at the coherence point
            if (tid == 0)      // announce: this block finished step t-1
                __hip_atomic_store(&flags[bx * 32], t, __ATOMIC_RELAXED,
                                   __HIP_MEMORY_SCOPE_AGENT);
            if (tid < 16)      // wait for all 16 blocks of own group
                while (__hip_atomic_load(&flags[(grp0 + tid) * 32],
                                         __ATOMIC_RELAXED,
                                         __HIP_MEMORY_SCOPE_AGENT) < t)
                    __builtin_amdgcn_s_sleep(1);
            __syncthreads();
        }

        // h(t): coherence-point reads (relaxed agent 8B atomics), 8x16B/thread
        const ushort* hrow = &hB[((long)(r0 + arow) * TS + t) * H_ + aseg * 8];
        uint4 av[8];
#pragma unroll
        for (int sl = 0; sl < 8; ++sl) {
            const unsigned long long* p8 =
                (const unsigned long long*)(hrow + sl * 64);
            unsigned long long lo = __hip_atomic_load(p8, __ATOMIC_RELAXED,
                                                      __HIP_MEMORY_SCOPE_AGENT);
            unsigned long long hi = __hip_atomic_load(p8 + 1, __ATOMIC_RELAXED,
                                                      __HIP_MEMORY_SCOPE_AGENT);
            av[sl].x = (uint)lo; av[sl].y = (uint)(lo >> 32);
            av[sl].z = (uint)hi; av[sl].w = (uint)(hi >> 32);
        }

#pragma unroll
        for (int sl = 0; sl < 8; ++sl)
            *(uint4*)&As[arow][sl * 64 + swz] = av[sl];
        __syncthreads();

        f32x4 acc[2][2] = {};   // [mtile][ntile]
#pragma unroll
        for (int ks = 0; ks < 16; ++ks) {
            const int e  = ks * 32 + q8;
            const int sl = e >> 6;
            const int c  = (e >> 3) & 7;
            bf16x8 a0 = *(const bf16x8*)&As[l15][sl * 64 + (((c + l15) & 7) << 3)];
            bf16x8 a1 = *(const bf16x8*)&As[16 + l15][sl * 64 + (((c + l15) & 7) << 3)];
            acc[0][0] = MFMA(a0, bfr[0][ks], acc[0][0]);
            acc[0][1] = MFMA(a0, bfr[1][ks], acc[0][1]);
            acc[1][0] = MFMA(a1, bfr[0][ks], acc[1][0]);
            acc[1][1] = MFMA(a1, bfr[1][ks], acc[1][1]);
        }

        // publish gate pre-acts (C layout: col=lane&15, row=(lane>>4)*4+rg)
#pragma unroll
        for (int mt = 0; mt < 2; ++mt)
#pragma unroll
            for (int nt = 0; nt < 2; ++nt)
#pragma unroll
                for (int rg2 = 0; rg2 < 4; ++rg2)
                    Gs[g][mt * 16 + (lane >> 4) * 4 + rg2][nt * 16 + l15] =
                        acc[mt][nt][rg2];
        __syncthreads();

        // fused cell update for 4 cols
        ushort hp[4];
#pragma unroll
        for (int cc = 0; cc < 4; ++cc) {
            uint xv0 = (cc < 2) ? xw[0].x : xw[0].y;
            uint xv1 = (cc < 2) ? xw[1].x : xw[1].y;
            uint xv2 = (cc < 2) ? xw[2].x : xw[2].y;
            uint xv3 = (cc < 2) ? xw[3].x : xw[3].y;
            int sh = (cc & 1) * 16;
            float gi = Gs[0][rr][jj + cc] + bf2f((ushort)(xv0 >> sh));
            float gf = Gs[1][rr][jj + cc] + bf2f((ushort)(xv1 >> sh));
            float gg = Gs[2][rr][jj + cc] + bf2f((ushort)(xv2 >> sh));
            float go = Gs[3][rr][jj + cc] + bf2f((ushort)(xv3 >> sh));
            cst[cc] = fsig(gf) * cst[cc] + fsig(gi) * ftanh(gg);
            hp[cc] = f2bf(fsig(go) * ftanh(cst[cc]));
        }
        unsigned long long pk = (unsigned long long)hp[0]
                              | ((unsigned long long)hp[1] << 16)
                              | ((unsigned long long)hp[2] << 32)
                              | ((unsigned long long)hp[3] << 48);
        // relaxed agent write-through: lands at the coherence point; ack'd
        // (vmcnt) before the next barrier's flag store can issue
        __hip_atomic_store(
            (unsigned long long*)&hB[((long)rg_ * TS + t + 1) * H_ + j0 + jj],
            pk, __ATOMIC_RELAXED, __HIP_MEMORY_SCOPE_AGENT);
    }
}

// ---------------------------------------------------------------------------
// K3a: U[m,c] = tanh(Hout[m,:] @ S1W^T) via bf16 MFMA (unchanged).
// ---------------------------------------------------------------------------
__global__ __launch_bounds__(256) void k_attn_mfma(
    const ushort* __restrict__ hfB, const ushort* __restrict__ hbB,
    const int* __restrict__ l1, const int* __restrict__ l2,
    const ushort* __restrict__ S1WB, float* __restrict__ U)
{
    const int r  = blockIdx.y >> 1;
    const int t0 = (blockIdx.y & 1) * 64;
    const int N0 = blockIdx.x * 64;
    const int L  = (r < B_) ? l1[r] : l2[r - B_];
    if (L <= t0) return;

    const int tid = threadIdx.x;
    const int lane = tid & 63, w = tid >> 6;
    const int wm = w & 1, wn = w >> 1;
    const int l15 = lane & 15, q8 = (lane >> 4) * 8;

    __shared__ __align__(16) ushort As[64][72];
    __shared__ __align__(16) ushort Bs[64][72];

    f32x4 acc[2][2] = {};

    for (int k0 = 0; k0 < 2 * H_; k0 += 64) {
#pragma unroll
        for (int p = 0; p < 2; ++p) {   // A: 64 rows x 64 k
            int u = tid + p * 256;
            int row = u >> 3, seg = u & 7;
            int tpos = t0 + row;
            int k = k0 + seg * 8;
            long idx;
            const ushort* src;
            if (k0 < H_) {
                src = hfB; idx = ((long)r * TS + tpos + 1) * H_ + k;
            } else {
                int tt = (tpos < L) ? (L - 1 - tpos) : tpos;
                src = hbB; idx = ((long)r * TS + tt + 1) * H_ + (k - H_);
            }
            *(uint4*)&As[row][seg * 8] = *(const uint4*)&src[idx];
        }
#pragma unroll
        for (int p = 0; p < 2; ++p) {   // B: 64 cols x 64 k
            int u = tid + p * 256;
            int row = u >> 3, seg = u & 7;
            *(uint4*)&Bs[row][seg * 8] =
                *(const uint4*)&S1WB[(long)(N0 + row) * (2 * H_) + k0 + seg * 8];
        }
        __syncthreads();
#pragma unroll
        for (int ks = 0; ks < 2; ++ks) {
            bf16x8 a0 = *(const bf16x8*)&As[wm * 32 + l15][ks * 32 + q8];
            bf16x8 a1 = *(const bf16x8*)&As[wm * 32 + 16 + l15][ks * 32 + q8];
            bf16x8 b0 = *(const bf16x8*)&Bs[wn * 32 + l15][ks * 32 + q8];
            bf16x8 b1 = *(const bf16x8*)&Bs[wn * 32 + 16 + l15][ks * 32 + q8];
            acc[0][0] = MFMA(a0, b0, acc[0][0]);
            acc[0][1] = MFMA(a0, b1, acc[0][1]);
            acc[1][0] = MFMA(a1, b0, acc[1][0]);
            acc[1][1] = MFMA(a1, b1, acc[1][1]);
        }
        __syncthreads();
    }
#pragma unroll
    for (int mt = 0; mt < 2; ++mt) {
        int m = r * T_ + t0 + wm * 32 + mt * 16 + (lane >> 4) * 4;
#pragma unroll
        for (int nt = 0; nt < 2; ++nt) {
            int col = N0 + wn * 32 + nt * 16 + l15;
#pragma unroll
            for (int rg = 0; rg < 4; ++rg)
                U[(long)(m + rg) * C_ + col] = ftanh(acc[mt][nt][rg]);
        }
    }
}

// ---------------------------------------------------------------------------
// K3b: scores = U@S2W, masked softmax, pooled = attn @ Hout.
// h reads vectorized to uint (bf16 pair) loads.
// ---------------------------------------------------------------------------
__global__ __launch_bounds__(256) void k_attn_pool(
    const ushort* __restrict__ hfB, const ushort* __restrict__ hbB,
    const float* __restrict__ U, const float* __restrict__ S2W,
    const int* __restrict__ l1, const int* __restrict__ l2,
    float* __restrict__ pooled)
{
    const int r = blockIdx.x;
    const int L = (r < B_) ? l1[r] : l2[r - B_];
    const int tid = threadIdx.x;
    const int lane = tid & 63, w = tid >> 6;

    __shared__ float att[T_];

    for (int tt = w; tt < T_; tt += 4) {
        float p = 0.0f;
        if (tt < L) {
            const float* u = &U[(long)(r * T_ + tt) * C_];
            p = u[lane] * S2W[lane] + u[lane + 64] * S2W[lane + 64]
              + u[lane + 128] * S2W[lane + 128] + u[lane + 192] * S2W[lane + 192];
            for (int off = 32; off; off >>= 1) p += __shfl_down(p, off);
        }
        if (lane == 0) att[tt] = p;
    }
    __syncthreads();

    float mx = -1e30f;
    for (int tt = 0; tt < L; ++tt) mx = fmaxf(mx, att[tt]);
    __syncthreads();
    if (tid < T_) att[tid] = (tid < L) ? __expf(att[tid] - mx) : 0.0f;
    __syncthreads();
    float sum = 0.0f;
    for (int tt = 0; tt < L; ++tt) sum += att[tt];
    float inv = 1.0f / sum;

    // pair index p in [0,512): p<256 -> hf dims {2p,2p+1}; else hb dims
    for (int p = tid; p < 512; p += 256) {
        float a0 = 0.0f, a1 = 0.0f;
        if (p < 256) {
            int d = p * 2;
            for (int tt = 0; tt < L; ++tt) {
                uint hv = *(const uint*)&hfB[((long)r * TS + tt + 1) * H_ + d];
                a0 += att[tt] * bf2f((ushort)(hv & 0xffff));
                a1 += att[tt] * bf2f((ushort)(hv >> 16));
            }
            pooled[(long)r * (2 * H_) + d]     = a0 * inv;
            pooled[(long)r * (2 * H_) + d + 1] = a1 * inv;
        } else {
            int d = (p - 256) * 2;
            for (int tt = 0; tt < L; ++tt) {
                uint hv = *(const uint*)&hbB[((long)r * TS + (L - tt)) * H_ + d];
                a0 += att[tt] * bf2f((ushort)(hv & 0xffff));
                a1 += att[tt] * bf2f((ushort)(hv >> 16));
            }
            pooled[(long)r * (2 * H_) + H_ + d]     = a0 * inv;
            pooled[(long)r * (2 * H_) + H_ + d + 1] = a1 * inv;
        }
    }
}

// ---------------------------------------------------------------------------
// K4a: om[b][mm] = merged[b] . mlpW[mm] + mlpb[mm] (unchanged).
// ---------------------------------------------------------------------------
__global__ __launch_bounds__(256) void k_mlp1(
    const float* __restrict__ pooled,
    const float* __restrict__ mlpW, const float* __restrict__ mlpb,
    float* __restrict__ om)
{
    const int mg = blockIdx.x;      // 0..7
    const int b  = blockIdx.y;      // 0..63
    const int tid = threadIdx.x;
    const int lane = tid & 63, w = tid >> 6;

    __shared__ __align__(16) float sm[2048];

#pragma unroll
    for (int it = 0; it < 8; ++it) {
        int d = tid + it * 256;
        float v;
        if (d < 1024) {
            v = pooled[(long)b * 1024 + d] + pooled[(long)(B_ + b) * 1024 + d];
        } else {
            int dd = d - 1024;
            float x = pooled[(long)b * 1024 + dd] - pooled[(long)(B_ + b) * 1024 + dd];
            v = x * x;
        }
        sm[d] = v;
    }
    __syncthreads();

    for (int i = 0; i < 16; ++i) {
        int mm = mg * 64 + w * 16 + i;
        const float* wrow = &mlpW[(long)mm * 2048];
        float ax = 0.f, ay = 0.f, az = 0.f, aw = 0.f;
#pragma unroll
        for (int it = 0; it < 8; ++it) {
            int k = it * 256 + lane * 4;
            float4 wv = *(const float4*)&wrow[k];
            float4 sv = *(const float4*)&sm[k];
            ax += wv.x * sv.x; ay += wv.y * sv.y;
            az += wv.z * sv.z; aw += wv.w * sv.w;
        }
        float ssum = (ax + ay) + (az + aw);
        for (int off = 32; off; off >>= 1) ssum += __shfl_down(ssum, off);
        if (lane == 0) om[(long)b * M_ + mm] = ssum + mlpb[mm];
    }
}

// K4b: out[b] = sigmoid(om[b] . outW + outb)   (CLS = 1)
__global__ __launch_bounds__(256) void k_final(
    const float* __restrict__ om,
    const float* __restrict__ outW, const float* __restrict__ outb,
    float* __restrict__ out)
{
    const int b = blockIdx.x;
    const int tid = threadIdx.x;
    __shared__ float red[256];
    float p = om[(long)b * M_ + tid] * outW[tid]
            + om[(long)b * M_ + 256 + tid] * outW[256 + tid];
    red[tid] = p;
    __syncthreads();
    for (int off = 128; off > 0; off >>= 1) {
        if (tid < off) red[tid] += red[tid + off];
        __syncthreads();
    }
    if (tid == 0) out[b] = 1.0f / (1.0f + __expf(-(red[0] + outb[0])));
}

// ---------------------------------------------------------------------------
extern "C" void kernel_launch(void* const* d_in, const int* in_sizes, int n_in,
                              void* d_out, int out_size, void* d_ws, size_t ws_size,
                              hipStream_t stream)
{
    const int*   s1    = (const int*)d_in[0];
    const int*   s2    = (const int*)d_in[1];
    const int*   l1    = (const int*)d_in[2];
    const int*   l2    = (const int*)d_in[3];
    const float* s1_h0 = (const float*)d_in[4];
    const float* s1_c0 = (const float*)d_in[5];
    const float* s2_h0 = (const float*)d_in[6];
    const float* s2_c0 = (const float*)d_in[7];
    const float* emb   = (const float*)d_in[8];
    const float* Wih_f = (const float*)d_in[9];
    const float* Whh_f = (const float*)d_in[10];
    const float* b_f   = (const float*)d_in[11];
    const float* Wih_b = (const float*)d_in[12];
    const float* Whh_b = (const float*)d_in[13];
    const float* b_b   = (const float*)d_in[14];
    const float* S1W   = (const float*)d_in[15];
    const float* S2W   = (const float*)d_in[16];
    const float* mlpW  = (const float*)d_in[17];
    const float* mlpb  = (const float*)d_in[18];
    const float* outW  = (const float*)d_in[19];
    const float* outb  = (const float*)d_in[20];
    float* out = (float*)d_out;

    // Workspace carve (all 16B-aligned)
    ushort* p16 = (ushort*)d_ws;
    ushort* embB  = p16;  p16 += (long)32000 * EP;
    ushort* WihBf = p16;  p16 += (long)G4 * EP;
    ushort* WihBb = p16;  p16 += (long)G4 * EP;
    ushort* WhhBf = p16;  p16 += (long)G4 * H_;
    ushort* WhhBb = p16;  p16 += (long)G4 * H_;
    ushort* S1WB  = p16;  p16 += (long)C_ * 2 * H_;
    ushort* xf    = p16;  p16 += (long)R_ * T_ * G4;
    ushort* xb    = p16;  p16 += (long)R_ * T_ * G4;
    ushort* hfB   = p16;  p16 += (long)R_ * TS * H_;
    ushort* hbB   = p16;  p16 += (long)R_ * TS * H_;
    float* pf = (float*)p16;
    float* U      = pf;   pf += (long)R_ * T_ * C_;
    float* pooled = pf;   pf += (long)R_ * 2 * H_;
    float* om     = pf;   pf += (long)B_ * M_;
    int*   bar    = (int*)pf;   // barrier state: flags[bx*32]

    // barrier init (memset node; graph-capture-safe; re-zeroed every replay)
    hipMemsetAsync(bar, 0, 64 * 1024, stream);

    // P0/P1: fused weight conversion + state init
    k_cvt_all<<<40448, 256, 0, stream>>>(emb, Wih_f, Wih_b, Whh_f, Whh_b, S1W,
                                         embB, WihBf, WihBb, WhhBf, WhhBb, S1WB);
    k_init<<<R_, 256, 0, stream>>>(s1_h0, s2_h0, hfB, hbB);

    // K1: input GEMM
    k_embed_mfma<<<dim3(16, 256, 2), 256, 0, stream>>>(
        s1, s2, l1, l2, embB, WihBf, WihBb, b_f, b_b, xf, xb);

    // K2: full recurrence in ONE persistent launch (128 blocks, j-width 32)
    k_recur<<<NB, 256, 0, stream>>>(xf, xb, hfB, hbB, WhhBf, WhhBb,
                                    s1_c0, s2_c0, bar);

    // K3: attention pooling
    k_attn_mfma<<<dim3(4, 256), 256, 0, stream>>>(hfB, hbB, l1, l2, S1WB, U);
    k_attn_pool<<<R_, 256, 0, stream>>>(hfB, hbB, U, S2W, l1, l2, pooled);

    // K4: MLP head
    k_mlp1<<<dim3(8, B_), 256, 0, stream>>>(pooled, mlpW, mlpb, om);
    k_final<<<B_, 256, 0, stream>>>(om, outW, outb, out);
}

// Round 9
// 800.787 us; speedup vs baseline: 3.9798x; 1.0328x over previous
//
#include <hip/hip_runtime.h>
#include <hip/hip_bf16.h>

// Problem constants (fixed by the reference)
#define B_  64
#define T_  128
#define E_  300
#define EP  320     // E padded to multiple of 32 for MFMA K-loop
#define H_  512
#define G4  2048    // 4*H
#define R_  128     // 2*B (s1+s2 batched; shared LSTM weights)
#define C_  256
#define M_  512
#define TS  (T_ + 1)  // h time slots: slot 0 = h0, slot t+1 = h(t)
#define NB  128     // persistent-kernel grid: 2 streams x 4 rowblocks x 16 jblocks
#define SENT 0xFFFFFFFFFFFFFFFFULL   // 4x bf16 NaN — unreachable by real h

typedef short bf16x8 __attribute__((ext_vector_type(8)));
typedef float f32x4  __attribute__((ext_vector_type(4)));
#define MFMA(a, b, c) __builtin_amdgcn_mfma_f32_16x16x32_bf16((a), (b), (c), 0, 0, 0)

__device__ __forceinline__ float fsig(float x) { return 1.0f / (1.0f + __expf(-x)); }
__device__ __forceinline__ float ftanh(float x) {
    float a = fminf(fabsf(x), 15.0f);
    float e = __expf(2.0f * a);
    return copysignf((e - 1.0f) / (e + 1.0f), x);
}
__device__ __forceinline__ ushort f2bf(float f) {
    __hip_bfloat16 h = __float2bfloat16(f);
    return *reinterpret_cast<ushort*>(&h);
}
__device__ __forceinline__ float bf2f(ushort u) {
    __hip_bfloat16 h = *reinterpret_cast<__hip_bfloat16*>(&u);
    return __bfloat162float(h);
}

// ---------------------------------------------------------------------------
// P0: fused f32 -> bf16 conversion for ALL weight tensors (one launch).
// ---------------------------------------------------------------------------
__global__ __launch_bounds__(256) void k_cvt_all(
    const float* __restrict__ emb,
    const float* __restrict__ Wih_f, const float* __restrict__ Wih_b,
    const float* __restrict__ Whh_f, const float* __restrict__ Whh_b,
    const float* __restrict__ S1W,
    ushort* __restrict__ embB,
    ushort* __restrict__ WihBf, ushort* __restrict__ WihBb,
    ushort* __restrict__ WhhBf, ushort* __restrict__ WhhBb,
    ushort* __restrict__ S1WB)
{
    int b = blockIdx.x;
    const float* src; ushort* dst; int r, sk, dk;
    if (b < 32000)      { src = emb;   dst = embB;  r = b;          sk = E_;    dk = EP; }
    else if (b < 34048) { src = Wih_f; dst = WihBf; r = b - 32000;  sk = E_;    dk = EP; }
    else if (b < 36096) { src = Wih_b; dst = WihBb; r = b - 34048;  sk = E_;    dk = EP; }
    else if (b < 38144) { src = Whh_f; dst = WhhBf; r = b - 36096;  sk = H_;    dk = H_; }
    else if (b < 40192) { src = Whh_b; dst = WhhBb; r = b - 38144;  sk = H_;    dk = H_; }
    else                { src = S1W;   dst = S1WB;  r = b - 40192;  sk = 2*H_;  dk = 2*H_; }
    for (int c = threadIdx.x; c < dk; c += 256)
        dst[(long)r * dk + c] = (c < sk) ? f2bf(src[(long)r * sk + c]) : (ushort)0;
}

// P1: init h slot 0 (bf16) from the h0 inputs (runs after the 0xFF memset).
__global__ __launch_bounds__(256) void k_init(
    const float* __restrict__ s1_h0, const float* __restrict__ s2_h0,
    ushort* __restrict__ hfB, ushort* __restrict__ hbB)
{
    const int r = blockIdx.x;                    // 0..127
    const int rl = (r < B_) ? r : r - B_;
    const float* h0 = (r < B_) ? s1_h0 : s2_h0;  // [2][B][H]
    for (int j = threadIdx.x; j < H_; j += 256) {
        hfB[(long)r * TS * H_ + j] = f2bf(h0[(long)0 * B_ * H_ + (long)rl * H_ + j]);
        hbB[(long)r * TS * H_ + j] = f2bf(h0[(long)1 * B_ * H_ + (long)rl * H_ + j]);
    }
}

// ---------------------------------------------------------------------------
// K1: embedding gather + input GEMM via bf16 MFMA (unchanged).
// ---------------------------------------------------------------------------
__global__ __launch_bounds__(256) void k_embed_mfma(
    const int* __restrict__ s1, const int* __restrict__ s2,
    const int* __restrict__ l1, const int* __restrict__ l2,
    const ushort* __restrict__ embB,
    const ushort* __restrict__ WihBf, const ushort* __restrict__ WihBb,
    const float* __restrict__ b_f, const float* __restrict__ b_b,
    ushort* __restrict__ xf, ushort* __restrict__ xb)
{
    const int dir = blockIdx.z;
    const int r   = blockIdx.y >> 1;
    const int t0  = (blockIdx.y & 1) * 64;
    const int N0  = blockIdx.x * 128;
    const int L   = (r < B_) ? l1[r] : l2[r - B_];
    if (L <= t0) return;

    const int tid = threadIdx.x;
    const int lane = tid & 63, w = tid >> 6;
    const int wm = w & 1, wn = w >> 1;
    const int l15 = lane & 15, q8 = (lane >> 4) * 8;

    __shared__ int toks[64];
    __shared__ __align__(16) ushort As[64][40];
    __shared__ __align__(16) ushort Bs[128][40];

    if (tid < 64) {
        int t  = t0 + tid;
        int tt = dir ? ((t < L) ? (L - 1 - t) : t) : t;
        toks[tid] = (r < B_) ? s1[r * T_ + tt] : s2[(r - B_) * T_ + tt];
    }
    __syncthreads();

    const ushort* Wih  = dir ? WihBb : WihBf;
    const float*  bias = dir ? b_b : b_f;

    f32x4 acc[2][4] = {};

    for (int k0 = 0; k0 < EP; k0 += 32) {
        {   // A: 64 rows x 32 k
            int row = tid >> 2, seg = tid & 3;
            *(uint4*)&As[row][seg * 8] =
                *(const uint4*)&embB[(long)toks[row] * EP + k0 + seg * 8];
        }
#pragma unroll
        for (int p = 0; p < 2; ++p) {   // B: 128 cols x 32 k
            int u = tid + p * 256;
            int row = u >> 2, seg = u & 3;
            *(uint4*)&Bs[row][seg * 8] =
                *(const uint4*)&Wih[(long)(N0 + row) * EP + k0 + seg * 8];
        }
        __syncthreads();
        bf16x8 af[2], bfr[4];
#pragma unroll
        for (int mt = 0; mt < 2; ++mt)
            af[mt] = *(const bf16x8*)&As[wm * 32 + mt * 16 + l15][q8];
#pragma unroll
        for (int nt = 0; nt < 4; ++nt)
            bfr[nt] = *(const bf16x8*)&Bs[wn * 64 + nt * 16 + l15][q8];
#pragma unroll
        for (int mt = 0; mt < 2; ++mt)
#pragma unroll
            for (int nt = 0; nt < 4; ++nt)
                acc[mt][nt] = MFMA(af[mt], bfr[nt], acc[mt][nt]);
        __syncthreads();
    }

    ushort* xout = dir ? xb : xf;
#pragma unroll
    for (int mt = 0; mt < 2; ++mt) {
        int m = r * T_ + t0 + wm * 32 + mt * 16 + (lane >> 4) * 4;
#pragma unroll
        for (int nt = 0; nt < 4; ++nt) {
            int col = N0 + wn * 64 + nt * 16 + l15;
            float bv = bias[col];
#pragma unroll
            for (int rg = 0; rg < 4; ++rg)
                xout[(long)(m + rg) * G4 + col] = f2bf(acc[mt][nt][rg] + bv);
        }
    }
}

// ---------------------------------------------------------------------------
// K2 v8: PERSISTENT recurrence, DATAFLOW sync (no barrier, no flags).
// h arrays pre-filled with 0xFF (4x bf16 NaN per 8B chunk — unreachable by
// real h, which is sig*tanh of finite values => exp<0xFF). Each h chunk is
// written exactly once (8B atomic store); consumers poll the chunks directly
// with relaxed agent loads until non-sentinel. Chain per step = one L3 hop
// (store lands -> poll hits), vs round-7/8's flag protocol (3-4 hops, which
// measured 3.65-3.8us/step invariant to barrier width).
// Blocks may run skewed; slots are time-indexed and never reused.
// LDS reuse safe: staging for t+1 starts only after sync#2 of t.
// ---------------------------------------------------------------------------
__global__ __launch_bounds__(256) void k_recur(
    const ushort* __restrict__ xf, const ushort* __restrict__ xb,
    ushort* __restrict__ hfB, ushort* __restrict__ hbB,
    const ushort* __restrict__ WhhBf, const ushort* __restrict__ WhhBb,
    const float* __restrict__ s1_c0, const float* __restrict__ s2_c0)
{
    const int bx = blockIdx.x;
    const int s  = bx >> 6;          // stream: 0 fwd, 1 bwd
    const int rb = (bx >> 4) & 3;    // row block of 32
    const int jb = bx & 15;          // j block of 32
    const int r0 = rb * 32, j0 = jb * 32;

    const ushort* xW  = s ? xb : xf;
    const ushort* Whh = s ? WhhBb : WhhBf;
    ushort* hB = s ? hbB : hfB;

    const int tid = threadIdx.x;
    const int lane = tid & 63;
    const int g = tid >> 6;          // wave = gate (i,f,g,o)
    const int l15 = lane & 15, q8 = (lane >> 4) * 8;

    __shared__ __align__(16) ushort As[32][520];   // 32 rows x 512 k, swizzled chunks
    __shared__ float Gs[4][32][33];                // gate pre-acts 32 x 32

    // Whh fragments resident in registers: wave g, 32 cols (2 n-tiles), K=512
    bf16x8 bfr[2][16];
#pragma unroll
    for (int nt = 0; nt < 2; ++nt) {
        const ushort* brow = &Whh[((long)g * H_ + j0 + nt * 16 + l15) * H_];
#pragma unroll
        for (int ks = 0; ks < 16; ++ks)
            bfr[nt][ks] = *(const bf16x8*)&brow[ks * 32 + q8];
    }

    // cell ownership: thread -> (row rr, 4 cols at jj)
    const int rr = tid >> 3, jj = (tid & 7) * 4;
    const int rg_ = r0 + rr;
    const int rl  = (rg_ < B_) ? rg_ : rg_ - B_;
    const float* c0p = (rg_ < B_) ? s1_c0 : s2_c0;   // [2][B][H]
    float cst[4];
#pragma unroll
    for (int cc = 0; cc < 4; ++cc)
        cst[cc] = c0p[(long)s * B_ * H_ + (long)rl * H_ + j0 + jj + cc];

    // A staging: thread -> (row arow, chunk aseg); chunk placed at (aseg+arow)&7
    const int arow = tid >> 3, aseg = tid & 7;
    const int swz = ((aseg + arow) & 7) * 8;

    for (int t = 0; t < T_; ++t) {
        // xW gate pre-activations (4 cols x 4 gates) — issued before the
        // h poll so their latency hides under the wait
        uint2 xw[4];
        const long xbase = ((long)rg_ * T_ + t) * G4 + j0 + jj;
#pragma unroll
        for (int gg = 0; gg < 4; ++gg)
            xw[gg] = *(const uint2*)&xW[xbase + gg * H_];

        // h(t): poll the data itself. 16 x 8B chunks; reload all each pass
        // (independent loads pipeline into one L3 latency per pass).
        const ushort* hrow = &hB[((long)(r0 + arow) * TS + t) * H_ + aseg * 8];
        unsigned long long hv[16];
        bool ok;
        do {
#pragma unroll
            for (int i = 0; i < 16; ++i) {
                const unsigned long long* p8 =
                    (const unsigned long long*)(hrow + (i >> 1) * 64 + (i & 1) * 4);
                hv[i] = __hip_atomic_load(p8, __ATOMIC_RELAXED,
                                          __HIP_MEMORY_SCOPE_AGENT);
            }
            ok = true;
#pragma unroll
            for (int i = 0; i < 16; ++i)
                ok = ok && (hv[i] != SENT);
        } while (!ok);

#pragma unroll
        for (int sl = 0; sl < 8; ++sl) {
            uint4 av;
            av.x = (uint)hv[2 * sl];       av.y = (uint)(hv[2 * sl] >> 32);
            av.z = (uint)hv[2 * sl + 1];   av.w = (uint)(hv[2 * sl + 1] >> 32);
            *(uint4*)&As[arow][sl * 64 + swz] = av;
        }
        __syncthreads();

        f32x4 acc[2][2] = {};   // [mtile][ntile]
#pragma unroll
        for (int ks = 0; ks < 16; ++ks) {
            const int e  = ks * 32 + q8;
            const int sl = e >> 6;
            const int c  = (e >> 3) & 7;
            bf16x8 a0 = *(const bf16x8*)&As[l15][sl * 64 + (((c + l15) & 7) << 3)];
            bf16x8 a1 = *(const bf16x8*)&As[16 + l15][sl * 64 + (((c + l15) & 7) << 3)];
            acc[0][0] = MFMA(a0, bfr[0][ks], acc[0][0]);
            acc[0][1] = MFMA(a0, bfr[1][ks], acc[0][1]);
            acc[1][0] = MFMA(a1, bfr[0][ks], acc[1][0]);
            acc[1][1] = MFMA(a1, bfr[1][ks], acc[1][1]);
        }

        // publish gate pre-acts (C layout: col=lane&15, row=(lane>>4)*4+rg)
#pragma unroll
        for (int mt = 0; mt < 2; ++mt)
#pragma unroll
            for (int nt = 0; nt < 2; ++nt)
#pragma unroll
                for (int rg2 = 0; rg2 < 4; ++rg2)
                    Gs[g][mt * 16 + (lane >> 4) * 4 + rg2][nt * 16 + l15] =
                        acc[mt][nt][rg2];
        __syncthreads();

        // fused cell update for 4 cols
        ushort hp[4];
#pragma unroll
        for (int cc = 0; cc < 4; ++cc) {
            uint xv0 = (cc < 2) ? xw[0].x : xw[0].y;
            uint xv1 = (cc < 2) ? xw[1].x : xw[1].y;
            uint xv2 = (cc < 2) ? xw[2].x : xw[2].y;
            uint xv3 = (cc < 2) ? xw[3].x : xw[3].y;
            int sh = (cc & 1) * 16;
            float gi = Gs[0][rr][jj + cc] + bf2f((ushort)(xv0 >> sh));
            float gf = Gs[1][rr][jj + cc] + bf2f((ushort)(xv1 >> sh));
            float gg = Gs[2][rr][jj + cc] + bf2f((ushort)(xv2 >> sh));
            float go = Gs[3][rr][jj + cc] + bf2f((ushort)(xv3 >> sh));
            cst[cc] = fsig(gf) * cst[cc] + fsig(gi) * ftanh(gg);
            hp[cc] = f2bf(fsig(go) * ftanh(cst[cc]));
        }
        unsigned long long pk = (unsigned long long)hp[0]
                              | ((unsigned long long)hp[1] << 16)
                              | ((unsigned long long)hp[2] << 32)
                              | ((unsigned long long)hp[3] << 48);
        // fire-and-forget: relaxed agent write-through; consumers poll for it
        __hip_atomic_store(
            (unsigned long long*)&hB[((long)rg_ * TS + t + 1) * H_ + j0 + jj],
            pk, __ATOMIC_RELAXED, __HIP_MEMORY_SCOPE_AGENT);
    }
}

// ---------------------------------------------------------------------------
// K3a: U[m,c] = tanh(Hout[m,:] @ S1W^T) via bf16 MFMA (unchanged).
// ---------------------------------------------------------------------------
__global__ __launch_bounds__(256) void k_attn_mfma(
    const ushort* __restrict__ hfB, const ushort* __restrict__ hbB,
    const int* __restrict__ l1, const int* __restrict__ l2,
    const ushort* __restrict__ S1WB, float* __restrict__ U)
{
    const int r  = blockIdx.y >> 1;
    const int t0 = (blockIdx.y & 1) * 64;
    const int N0 = blockIdx.x * 64;
    const int L  = (r < B_) ? l1[r] : l2[r - B_];
    if (L <= t0) return;

    const int tid = threadIdx.x;
    const int lane = tid & 63, w = tid >> 6;
    const int wm = w & 1, wn = w >> 1;
    const int l15 = lane & 15, q8 = (lane >> 4) * 8;

    __shared__ __align__(16) ushort As[64][72];
    __shared__ __align__(16) ushort Bs[64][72];

    f32x4 acc[2][2] = {};

    for (int k0 = 0; k0 < 2 * H_; k0 += 64) {
#pragma unroll
        for (int p = 0; p < 2; ++p) {   // A: 64 rows x 64 k
            int u = tid + p * 256;
            int row = u >> 3, seg = u & 7;
            int tpos = t0 + row;
            int k = k0 + seg * 8;
            long idx;
            const ushort* src;
            if (k0 < H_) {
                src = hfB; idx = ((long)r * TS + tpos + 1) * H_ + k;
            } else {
                int tt = (tpos < L) ? (L - 1 - tpos) : tpos;
                src = hbB; idx = ((long)r * TS + tt + 1) * H_ + (k - H_);
            }
            *(uint4*)&As[row][seg * 8] = *(const uint4*)&src[idx];
        }
#pragma unroll
        for (int p = 0; p < 2; ++p) {   // B: 64 cols x 64 k
            int u = tid + p * 256;
            int row = u >> 3, seg = u & 7;
            *(uint4*)&Bs[row][seg * 8] =
                *(const uint4*)&S1WB[(long)(N0 + row) * (2 * H_) + k0 + seg * 8];
        }
        __syncthreads();
#pragma unroll
        for (int ks = 0; ks < 2; ++ks) {
            bf16x8 a0 = *(const bf16x8*)&As[wm * 32 + l15][ks * 32 + q8];
            bf16x8 a1 = *(const bf16x8*)&As[wm * 32 + 16 + l15][ks * 32 + q8];
            bf16x8 b0 = *(const bf16x8*)&Bs[wn * 32 + l15][ks * 32 + q8];
            bf16x8 b1 = *(const bf16x8*)&Bs[wn * 32 + 16 + l15][ks * 32 + q8];
            acc[0][0] = MFMA(a0, b0, acc[0][0]);
            acc[0][1] = MFMA(a0, b1, acc[0][1]);
            acc[1][0] = MFMA(a1, b0, acc[1][0]);
            acc[1][1] = MFMA(a1, b1, acc[1][1]);
        }
        __syncthreads();
    }
#pragma unroll
    for (int mt = 0; mt < 2; ++mt) {
        int m = r * T_ + t0 + wm * 32 + mt * 16 + (lane >> 4) * 4;
#pragma unroll
        for (int nt = 0; nt < 2; ++nt) {
            int col = N0 + wn * 32 + nt * 16 + l15;
#pragma unroll
            for (int rg = 0; rg < 4; ++rg)
                U[(long)(m + rg) * C_ + col] = ftanh(acc[mt][nt][rg]);
        }
    }
}

// ---------------------------------------------------------------------------
// K3b: scores = U@S2W, masked softmax, pooled = attn @ Hout (unchanged).
// ---------------------------------------------------------------------------
__global__ __launch_bounds__(256) void k_attn_pool(
    const ushort* __restrict__ hfB, const ushort* __restrict__ hbB,
    const float* __restrict__ U, const float* __restrict__ S2W,
    const int* __restrict__ l1, const int* __restrict__ l2,
    float* __restrict__ pooled)
{
    const int r = blockIdx.x;
    const int L = (r < B_) ? l1[r] : l2[r - B_];
    const int tid = threadIdx.x;
    const int lane = tid & 63, w = tid >> 6;

    __shared__ float att[T_];

    for (int tt = w; tt < T_; tt += 4) {
        float p = 0.0f;
        if (tt < L) {
            const float* u = &U[(long)(r * T_ + tt) * C_];
            p = u[lane] * S2W[lane] + u[lane + 64] * S2W[lane + 64]
              + u[lane + 128] * S2W[lane + 128] + u[lane + 192] * S2W[lane + 192];
            for (int off = 32; off; off >>= 1) p += __shfl_down(p, off);
        }
        if (lane == 0) att[tt] = p;
    }
    __syncthreads();

    float mx = -1e30f;
    for (int tt = 0; tt < L; ++tt) mx = fmaxf(mx, att[tt]);
    __syncthreads();
    if (tid < T_) att[tid] = (tid < L) ? __expf(att[tid] - mx) : 0.0f;
    __syncthreads();
    float sum = 0.0f;
    for (int tt = 0; tt < L; ++tt) sum += att[tt];
    float inv = 1.0f / sum;

    for (int p = tid; p < 512; p += 256) {
        float a0 = 0.0f, a1 = 0.0f;
        if (p < 256) {
            int d = p * 2;
            for (int tt = 0; tt < L; ++tt) {
                uint hv = *(const uint*)&hfB[((long)r * TS + tt + 1) * H_ + d];
                a0 += att[tt] * bf2f((ushort)(hv & 0xffff));
                a1 += att[tt] * bf2f((ushort)(hv >> 16));
            }
            pooled[(long)r * (2 * H_) + d]     = a0 * inv;
            pooled[(long)r * (2 * H_) + d + 1] = a1 * inv;
        } else {
            int d = (p - 256) * 2;
            for (int tt = 0; tt < L; ++tt) {
                uint hv = *(const uint*)&hbB[((long)r * TS + (L - tt)) * H_ + d];
                a0 += att[tt] * bf2f((ushort)(hv & 0xffff));
                a1 += att[tt] * bf2f((ushort)(hv >> 16));
            }
            pooled[(long)r * (2 * H_) + H_ + d]     = a0 * inv;
            pooled[(long)r * (2 * H_) + H_ + d + 1] = a1 * inv;
        }
    }
}

// ---------------------------------------------------------------------------
// K4a: om[b][mm] = merged[b] . mlpW[mm] + mlpb[mm] (unchanged).
// ---------------------------------------------------------------------------
__global__ __launch_bounds__(256) void k_mlp1(
    const float* __restrict__ pooled,
    const float* __restrict__ mlpW, const float* __restrict__ mlpb,
    float* __restrict__ om)
{
    const int mg = blockIdx.x;      // 0..7
    const int b  = blockIdx.y;      // 0..63
    const int tid = threadIdx.x;
    const int lane = tid & 63, w = tid >> 6;

    __shared__ __align__(16) float sm[2048];

#pragma unroll
    for (int it = 0; it < 8; ++it) {
        int d = tid + it * 256;
        float v;
        if (d < 1024) {
            v = pooled[(long)b * 1024 + d] + pooled[(long)(B_ + b) * 1024 + d];
        } else {
            int dd = d - 1024;
            float x = pooled[(long)b * 1024 + dd] - pooled[(long)(B_ + b) * 1024 + dd];
            v = x * x;
        }
        sm[d] = v;
    }
    __syncthreads();

    for (int i = 0; i < 16; ++i) {
        int mm = mg * 64 + w * 16 + i;
        const float* wrow = &mlpW[(long)mm * 2048];
        float ax = 0.f, ay = 0.f, az = 0.f, aw = 0.f;
#pragma unroll
        for (int it = 0; it < 8; ++it) {
            int k = it * 256 + lane * 4;
            float4 wv = *(const float4*)&wrow[k];
            float4 sv = *(const float4*)&sm[k];
            ax += wv.x * sv.x; ay += wv.y * sv.y;
            az += wv.z * sv.z; aw += wv.w * sv.w;
        }
        float ssum = (ax + ay) + (az + aw);
        for (int off = 32; off; off >>= 1) ssum += __shfl_down(ssum, off);
        if (lane == 0) om[(long)b * M_ + mm] = ssum + mlpb[mm];
    }
}

// K4b: out[b] = sigmoid(om[b] . outW + outb)   (CLS = 1)
__global__ __launch_bounds__(256) void k_final(
    const float* __restrict__ om,
    const float* __restrict__ outW, const float* __restrict__ outb,
    float* __restrict__ out)
{
    const int b = blockIdx.x;
    const int tid = threadIdx.x;
    __shared__ float red[256];
    float p = om[(long)b * M_ + tid] * outW[tid]
            + om[(long)b * M_ + 256 + tid] * outW[256 + tid];
    red[tid] = p;
    __syncthreads();
    for (int off = 128; off > 0; off >>= 1) {
        if (tid < off) red[tid] += red[tid + off];
        __syncthreads();
    }
    if (tid == 0) out[b] = 1.0f / (1.0f + __expf(-(red[0] + outb[0])));
}

// ---------------------------------------------------------------------------
extern "C" void kernel_launch(void* const* d_in, const int* in_sizes, int n_in,
                              void* d_out, int out_size, void* d_ws, size_t ws_size,
                              hipStream_t stream)
{
    const int*   s1    = (const int*)d_in[0];
    const int*   s2    = (const int*)d_in[1];
    const int*   l1    = (const int*)d_in[2];
    const int*   l2    = (const int*)d_in[3];
    const float* s1_h0 = (const float*)d_in[4];
    const float* s1_c0 = (const float*)d_in[5];
    const float* s2_h0 = (const float*)d_in[6];
    const float* s2_c0 = (const float*)d_in[7];
    const float* emb   = (const float*)d_in[8];
    const float* Wih_f = (const float*)d_in[9];
    const float* Whh_f = (const float*)d_in[10];
    const float* b_f   = (const float*)d_in[11];
    const float* Wih_b = (const float*)d_in[12];
    const float* Whh_b = (const float*)d_in[13];
    const float* b_b   = (const float*)d_in[14];
    const float* S1W   = (const float*)d_in[15];
    const float* S2W   = (const float*)d_in[16];
    const float* mlpW  = (const float*)d_in[17];
    const float* mlpb  = (const float*)d_in[18];
    const float* outW  = (const float*)d_in[19];
    const float* outb  = (const float*)d_in[20];
    float* out = (float*)d_out;

    // Workspace carve (all 16B-aligned)
    ushort* p16 = (ushort*)d_ws;
    ushort* embB  = p16;  p16 += (long)32000 * EP;
    ushort* WihBf = p16;  p16 += (long)G4 * EP;
    ushort* WihBb = p16;  p16 += (long)G4 * EP;
    ushort* WhhBf = p16;  p16 += (long)G4 * H_;
    ushort* WhhBb = p16;  p16 += (long)G4 * H_;
    ushort* S1WB  = p16;  p16 += (long)C_ * 2 * H_;
    ushort* xf    = p16;  p16 += (long)R_ * T_ * G4;
    ushort* xb    = p16;  p16 += (long)R_ * T_ * G4;
    ushort* hfB   = p16;  p16 += (long)R_ * TS * H_;
    ushort* hbB   = p16;  p16 += (long)R_ * TS * H_;
    float* pf = (float*)p16;
    float* U      = pf;   pf += (long)R_ * T_ * C_;
    float* pooled = pf;   pf += (long)R_ * 2 * H_;
    float* om     = pf;   pf += (long)B_ * M_;

    // sentinel-fill h arrays (0xFF bytes -> every bf16 = NaN, every 8B chunk
    // = SENT); k_init then writes real h0 into slot 0. hfB/hbB are contiguous.
    hipMemsetAsync(hfB, 0xFF, (size_t)2 * R_ * TS * H_ * sizeof(ushort), stream);

    // P0/P1: fused weight conversion + state init
    k_cvt_all<<<40448, 256, 0, stream>>>(emb, Wih_f, Wih_b, Whh_f, Whh_b, S1W,
                                         embB, WihBf, WihBb, WhhBf, WhhBb, S1WB);
    k_init<<<R_, 256, 0, stream>>>(s1_h0, s2_h0, hfB, hbB);

    // K1: input GEMM
    k_embed_mfma<<<dim3(16, 256, 2), 256, 0, stream>>>(
        s1, s2, l1, l2, embB, WihBf, WihBb, b_f, b_b, xf, xb);

    // K2: full recurrence in ONE persistent launch (dataflow sync)
    k_recur<<<NB, 256, 0, stream>>>(xf, xb, hfB, hbB, WhhBf, WhhBb,
                                    s1_c0, s2_c0);

    // K3: attention pooling
    k_attn_mfma<<<dim3(4, 256), 256, 0, stream>>>(hfB, hbB, l1, l2, S1WB, U);
    k_attn_pool<<<R_, 256, 0, stream>>>(hfB, hbB, U, S2W, l1, l2, pooled);

    // K4: MLP head
    k_mlp1<<<dim3(8, B_), 256, 0, stream>>>(pooled, mlpW, mlpb, om);
    k_final<<<B_, 256, 0, stream>>>(om, outW, outb, out);
}